// Round 11
// baseline (319.033 us; speedup 1.0000x reference)
//
#include <hip/hip_runtime.h>
#include <math.h>

#define N_NODES 20000
#define N_EDGES 320000
#define N_TILES 1250   // N_NODES / 16

typedef __attribute__((ext_vector_type(8))) short bf16x8;
typedef __attribute__((ext_vector_type(4))) float f32x4;
typedef __attribute__((ext_vector_type(2))) unsigned u32x2;
typedef __attribute__((ext_vector_type(4))) unsigned u32x4;

__device__ __forceinline__ float silu_f(float x) {
    return x / (1.0f + __expf(-x));
}
__device__ __forceinline__ short f2bf(float x) {
    union { float f; unsigned u; } v; v.f = x;
    unsigned r = (v.u + 0x7FFFu + ((v.u >> 16) & 1u)) >> 16;
    return (short)r;
}
__device__ __forceinline__ float blo(unsigned u) { return __uint_as_float(u << 16); }
__device__ __forceinline__ float bhi(unsigned u) { return __uint_as_float(u & 0xFFFF0000u); }
__device__ __forceinline__ unsigned cvt_pk(float lo, float hi) {
    unsigned r;
    asm("v_cvt_pk_bf16_f32 %0, %1, %2" : "=v"(r) : "v"(lo), "v"(hi));
    return r;
}
#define MFMA16(a, b, c) __builtin_amdgcn_mfma_f32_16x16x32_bf16((a), (b), (c), 0, 0, 0)

// ---------------- sort pass ----------------
__global__ __launch_bounds__(256) void s_hist(const int* __restrict__ eidx,
                                              int* __restrict__ cnt) {
    const int e = blockIdx.x * 256 + threadIdx.x;
    if (e < N_EDGES) atomicAdd(&cnt[eidx[e]], 1);
}

__global__ __launch_bounds__(1024) void s_scan(int* __restrict__ cnt,
                                               int* __restrict__ start) {
    const int tid = threadIdx.x;
    const int base = tid * 20;
    int vals[20];
    int sum = 0;
    #pragma unroll
    for (int j = 0; j < 20; ++j) {
        const int i = base + j;
        const int v = (i < N_NODES) ? cnt[i] : 0;
        vals[j] = sum;
        sum += v;
    }
    const int lane = tid & 63, wv = tid >> 6;
    int x = sum;
    #pragma unroll
    for (int off = 1; off < 64; off <<= 1) {
        const int t = __shfl_up(x, off);
        if (lane >= off) x += t;
    }
    __shared__ int wtot[16];
    if (lane == 63) wtot[wv] = x;
    __syncthreads();
    int wpref = 0;
    for (int k = 0; k < wv; ++k) wpref += wtot[k];
    const int excl = wpref + x - sum;
    #pragma unroll
    for (int j = 0; j < 20; ++j) {
        const int i = base + j;
        if (i < N_NODES) {
            const int s = excl + vals[j];
            start[i] = s;
            cnt[i] = s;   // cnt doubles as cursor
        }
    }
    if (tid == 1023) start[N_NODES] = wpref + x;
}

__global__ __launch_bounds__(256) void s_scatter(const int* __restrict__ eidx,
                                                 const float* __restrict__ esh,
                                                 int* __restrict__ cursor,
                                                 int* __restrict__ perm,
                                                 int* __restrict__ dst_perm,
                                                 int* __restrict__ node_perm,
                                                 float* __restrict__ esh_perm) {
    const int e = blockIdx.x * 256 + threadIdx.x;
    if (e >= N_EDGES) return;
    const int src = eidx[e];
    const int pos = atomicAdd(&cursor[src], 1);
    perm[pos] = e;
    dst_perm[pos] = eidx[N_EDGES + e];
    node_perm[pos] = src;
    *(float4*)(esh_perm + (size_t)pos * 4) = *(const float4*)(esh + (size_t)e * 4);
}

// ---------------- weight prepack (round-8 layouts) ----------------
__global__ __launch_bounds__(256) void k_pack(
    const float* __restrict__ fcw1, const float* __restrict__ fcw2,
    const float* __restrict__ fcw3,
    const float* __restrict__ w1s, const float* __restrict__ wscs,
    const float* __restrict__ w1v, const float* __restrict__ wscv,
    const float* __restrict__ w2s, const float* __restrict__ w2v,
    short* __restrict__ w1A, short* __restrict__ w2A, short* __restrict__ w3A,
    short* __restrict__ wp1, short* __restrict__ wp2)
{
    const int tid = blockIdx.x * 256 + threadIdx.x;
    const int nthr = gridDim.x * 256;
    for (int i = tid; i < 4*64*8; i += nthr) {           // fc_w1^T, K padded
        const int j = i & 7, lane = (i >> 3) & 63, t = i >> 9;
        const int k = (lane >> 4) * 8 + j, row = t*16 + (lane & 15);
        w1A[i] = (k < 8) ? f2bf(fcw1[k*64 + row]) : (short)0;
    }
    for (int i = tid; i < 8*64*8; i += nthr) {           // fc_w2^T
        const int j = i & 7, lane = (i >> 3) & 63, kk = (i >> 9) & 1, t = i >> 10;
        const int k = kk*32 + (lane >> 4)*8 + j, row = t*16 + (lane & 15);
        w2A[i] = f2bf(fcw2[k*64 + row]);
    }
    for (int i = tid; i < 32*64*8; i += nthr) {          // fc_w3^T (wD * 1/sqrt3 folded)
        const int j = i & 7, lane = (i >> 3) & 63, kk = (i >> 9) & 1, T = i >> 10;
        const int k = kk*32 + (lane >> 4)*8 + j, c = T*16 + (lane & 15);
        const float s = (c >= 192) ? 0.5773502691896258f : 1.0f;
        w3A[i] = f2bf(fcw3[(size_t)k*256 + c] * s);
    }
    for (int i = tid; i < 4096; i += nthr) {             // k1 weights (64x64)
        const int j = i & 7, lane = (i >> 3) & 63, kk = (i >> 9) & 1, vt = i >> 10;
        const int row = vt*16 + (lane & 15), k = kk*32 + (lane >> 4)*8 + j;
        wp1[i]         = f2bf(w1s [k*64 + row]);
        wp1[4096 + i]  = f2bf(wscs[k*64 + row]);
        wp1[8192 + i]  = f2bf(w1v [k*64 + row]);
        wp1[12288 + i] = f2bf(wscv[k*64 + row]);
    }
    for (int i = tid; i < 8192; i += nthr) {             // k3 weights (128x64), no remap
        const int j = i & 7, lane = (i >> 3) & 63, kk = (i >> 9) & 3, vt = i >> 11;
        const int row = vt*16 + (lane & 15), k = kk*32 + (lane >> 4)*8 + j;
        wp2[i]        = f2bf(w2s[k*64 + row]);
        wp2[8192 + i] = f2bf(w2v[k*64 + row]);
    }
}

// ---------------- K1: node pre-GEMMs via MFMA, bf16-packed outputs ----------------
__global__ __launch_bounds__(256) void k1_mfma(
    const float* __restrict__ nh, const short* __restrict__ wp1,
    short* __restrict__ ydata, short* __restrict__ scpack)
{
    const int lane = threadIdx.x & 63;
    const int tile = blockIdx.x * 4 + (threadIdx.x >> 6);
    if (tile >= N_TILES) return;
    const int l15 = lane & 15, lhi = lane >> 4;
    const int n = tile*16 + l15;
    const float* row = nh + (size_t)n * 256;
    const f32x4 zz = {0.f, 0.f, 0.f, 0.f};
    f32x4 acc[8][4];
    #pragma unroll
    for (int c = 0; c < 8; ++c)
        #pragma unroll
        for (int vt = 0; vt < 4; ++vt) acc[c][vt] = zz;

    #pragma unroll
    for (int kk = 0; kk < 2; ++kk) {
        const int k0 = kk*32 + lhi*8;
        const float4 s0 = *(const float4*)(row + k0);
        const float4 s1 = *(const float4*)(row + k0 + 4);
        float4 vv[6];
        #pragma unroll
        for (int q = 0; q < 6; ++q) vv[q] = *(const float4*)(row + 64 + 3*k0 + q*4);
        const float* vf = (const float*)vv;
        union { u32x4 u; bf16x8 v; } bs, b0, b1, b2;
        bs.u[0] = cvt_pk(s0.x, s0.y); bs.u[1] = cvt_pk(s0.z, s0.w);
        bs.u[2] = cvt_pk(s1.x, s1.y); bs.u[3] = cvt_pk(s1.z, s1.w);
        #pragma unroll
        for (int q = 0; q < 4; ++q) {
            b0.u[q] = cvt_pk(vf[6*q + 0], vf[6*q + 3]);
            b1.u[q] = cvt_pk(vf[6*q + 1], vf[6*q + 4]);
            b2.u[q] = cvt_pk(vf[6*q + 2], vf[6*q + 5]);
        }
        #pragma unroll
        for (int vt = 0; vt < 4; ++vt) {
            const int fo = ((vt*2 + kk)*64 + lane)*8;
            const bf16x8 a_ys = *(const bf16x8*)&wp1[fo];
            const bf16x8 a_ss = *(const bf16x8*)&wp1[4096 + fo];
            const bf16x8 a_yv = *(const bf16x8*)&wp1[8192 + fo];
            const bf16x8 a_sv = *(const bf16x8*)&wp1[12288 + fo];
            acc[0][vt] = MFMA16(a_ys, bs.v, acc[0][vt]);
            acc[1][vt] = MFMA16(a_ss, bs.v, acc[1][vt]);
            acc[2][vt] = MFMA16(a_yv, b0.v, acc[2][vt]);
            acc[3][vt] = MFMA16(a_yv, b1.v, acc[3][vt]);
            acc[4][vt] = MFMA16(a_yv, b2.v, acc[4][vt]);
            acc[5][vt] = MFMA16(a_sv, b0.v, acc[5][vt]);
            acc[6][vt] = MFMA16(a_sv, b1.v, acc[6][vt]);
            acc[7][vt] = MFMA16(a_sv, b2.v, acc[7][vt]);
        }
    }
    #pragma unroll
    for (int vt = 0; vt < 4; ++vt)
        #pragma unroll
        for (int r = 0; r < 4; ++r) {
            const int v = vt*16 + lhi*4 + r;
            u32x2 yo, so;
            yo[0] = cvt_pk(acc[0][vt][r]*0.125f, acc[2][vt][r]*0.125f);
            yo[1] = cvt_pk(acc[3][vt][r]*0.125f, acc[4][vt][r]*0.125f);
            so[0] = cvt_pk(acc[1][vt][r]*0.125f, acc[5][vt][r]*0.125f);
            so[1] = cvt_pk(acc[6][vt][r]*0.125f, acc[7][vt][r]*0.125f);
            *(u32x2*)&ydata [((size_t)n*64 + v)*4] = yo;
            *(u32x2*)&scpack[((size_t)n*64 + v)*4] = so;
        }
}

// ---------------- K_msg: fused edge MLP + message + segment-sum (round-8 structure,
// message loads batched 8-deep for ILP) ----------------
__global__ __launch_bounds__(256) void k_msg(
    const float* __restrict__ ea, const int* __restrict__ perm,
    const int* __restrict__ dst_perm, const int* __restrict__ node_perm,
    const int* __restrict__ start, const float* __restrict__ esh_perm,
    const short* __restrict__ w1A, const short* __restrict__ w2A,
    const short* __restrict__ w3A, const short* __restrict__ ydata,
    float* __restrict__ ncat)
{
    __shared__ short hb1[4][1024];
    __shared__ short hb2[4][1024];
    __shared__ short wslab[4][4096];   // [wave][16 window-slots][64 v][4 g] u16 (swizzled)
    const int lane = threadIdx.x & 63, w = threadIdx.x >> 6;
    const int l15 = lane & 15, lhi = lane >> 4;
    const int wbase = (blockIdx.x * 4 + w) * 64;
    short* h1b = hb1[w];
    short* h2b = hb2[w];
    short* slab = wslab[w];
    const int swz = (l15 & 7) << 4;
    const f32x4 zz = {0.f, 0.f, 0.f, 0.f};

    // segment tracking (wave-uniform)
    int cur = node_perm[wbase];
    int s_lo = start[cur], s_hi = start[cur + 1];
    float acc0=0.f, acc1=0.f, av0=0.f, av1=0.f, av2=0.f, bv0=0.f, bv1=0.f, bv2=0.f;

    auto flushfn = [&]() {
        float* b = ncat + ((size_t)cur*64 + lane)*8;
        if (s_lo >= wbase && s_hi <= wbase + 64) {
            const float4 x0 = { acc0, av0, av1, av2 };
            const float4 x1 = { acc1, bv0, bv1, bv2 };
            *(float4*)b = x0;
            *(float4*)(b + 4) = x1;
        } else {
            atomicAdd(b + 0, acc0); atomicAdd(b + 1, av0);
            atomicAdd(b + 2, av1); atomicAdd(b + 3, av2);
            atomicAdd(b + 4, acc1); atomicAdd(b + 5, bv0);
            atomicAdd(b + 6, bv1); atomicAdd(b + 7, bv2);
        }
    };

    for (int sb = 0; sb < 4; ++sb) {
        // ---- L1: edge_attr -> h1 ----
        bf16x8 a1[4];
        #pragma unroll
        for (int t = 0; t < 4; ++t)
            a1[t] = *(const bf16x8*)&w1A[(t*64 + lane)*8];
        bf16x8 bea = {0,0,0,0,0,0,0,0};
        if (lhi == 0) {
            const int e = perm[wbase + sb*16 + l15];
            const float4 p0 = *(const float4*)(ea + (size_t)e*8);
            const float4 p1 = *(const float4*)(ea + (size_t)e*8 + 4);
            union { u32x4 u; bf16x8 v; } tu;
            tu.u[0] = cvt_pk(p0.x, p0.y);
            tu.u[1] = cvt_pk(p0.z, p0.w);
            tu.u[2] = cvt_pk(p1.x, p1.y);
            tu.u[3] = cvt_pk(p1.z, p1.w);
            bea = tu.v;
        }
        f32x4 d1[4];
        #pragma unroll
        for (int t = 0; t < 4; ++t)
            d1[t] = MFMA16(a1[t], bea, zz);
        #pragma unroll
        for (int t = 0; t < 4; ++t) {
            const float s0 = silu_f(d1[t][0] * 0.35355339059327373f);
            const float s1 = silu_f(d1[t][1] * 0.35355339059327373f);
            const float s2 = silu_f(d1[t][2] * 0.35355339059327373f);
            const float s3 = silu_f(d1[t][3] * 0.35355339059327373f);
            u32x2 pk; pk[0] = cvt_pk(s0, s1); pk[1] = cvt_pk(s2, s3);
            const int byt = (l15*128 + t*32 + lhi*8) ^ swz;
            *(u32x2*)((char*)h1b + byt) = pk;
        }
        // ---- L2 ----
        bf16x8 a2[4][2];
        #pragma unroll
        for (int t = 0; t < 4; ++t)
            #pragma unroll
            for (int kk = 0; kk < 2; ++kk)
                a2[t][kk] = *(const bf16x8*)&w2A[((t*2 + kk)*64 + lane)*8];
        bf16x8 bh1[2];
        #pragma unroll
        for (int kk = 0; kk < 2; ++kk)
            bh1[kk] = *(const bf16x8*)((const char*)h1b + ((l15*128 + kk*64 + lhi*16) ^ swz));
        f32x4 d2[4];
        #pragma unroll
        for (int t = 0; t < 4; ++t) {
            d2[t] = MFMA16(a2[t][0], bh1[0], zz);
            d2[t] = MFMA16(a2[t][1], bh1[1], d2[t]);
        }
        #pragma unroll
        for (int t = 0; t < 4; ++t) {
            const float s0 = silu_f(d2[t][0] * 0.125f) * 0.125f;
            const float s1 = silu_f(d2[t][1] * 0.125f) * 0.125f;
            const float s2 = silu_f(d2[t][2] * 0.125f) * 0.125f;
            const float s3 = silu_f(d2[t][3] * 0.125f) * 0.125f;
            u32x2 pk; pk[0] = cvt_pk(s0, s1); pk[1] = cvt_pk(s2, s3);
            const int byt = (l15*128 + t*32 + lhi*8) ^ swz;
            *(u32x2*)((char*)h2b + byt) = pk;
        }
        bf16x8 bh2[2];
        #pragma unroll
        for (int kk = 0; kk < 2; ++kk)
            bh2[kk] = *(const bf16x8*)((const char*)h2b + ((l15*128 + kk*64 + lhi*16) ^ swz));

        // ---- L3: 16 ch-tiles -> swizzled LDS slab (window-local slot = l15) ----
        #pragma unroll
        for (int T = 0; T < 16; ++T) {
            const bf16x8 a30 = *(const bf16x8*)&w3A[((T*2 + 0)*64 + lane)*8];
            const bf16x8 a31 = *(const bf16x8*)&w3A[((T*2 + 1)*64 + lane)*8];
            f32x4 d = MFMA16(a30, bh2[0], zz);
            d = MFMA16(a31, bh2[1], d);
            const int g = T >> 2;
            const int vb = (T & 3)*16 + lhi*4;
            const unsigned p01 = cvt_pk(d[0], d[1]);
            const unsigned p23 = cvt_pk(d[2], d[3]);
            short* sl = slab + l15*256;   // 512B per window-slot
            const int m = l15 & 7;
            sl[(((vb + 0) ^ m) << 2) + g] = (short)(p01 & 0xFFFFu);
            sl[(((vb + 1) ^ m) << 2) + g] = (short)(p01 >> 16);
            sl[(((vb + 2) ^ m) << 2) + g] = (short)(p23 & 0xFFFFu);
            sl[(((vb + 3) ^ m) << 2) + g] = (short)(p23 >> 16);
        }

        // ---- message loop: 2 groups of 8, loads batched for ILP ----
        for (int g2 = 0; g2 < 2; ++g2) {
            u32x2 wv[8], yd[8];
            float4 sh[8];
            #pragma unroll
            for (int j = 0; j < 8; ++j) {
                const int i = g2*8 + j;
                const int slot = wbase + sb*16 + i;
                wv[j] = *(const u32x2*)(slab + i*256 + ((lane ^ (i & 7)) << 2));
                sh[j] = *(const float4*)(esh_perm + (size_t)slot*4);
                const int dst = dst_perm[slot];
                yd[j] = *(const u32x2*)&ydata[((size_t)dst*64 + lane)*4];
            }
            #pragma unroll
            for (int j = 0; j < 8; ++j) {
                const int slot = wbase + sb*16 + g2*8 + j;
                if (slot >= s_hi) {           // wave-uniform node boundary
                    flushfn();
                    cur = node_perm[slot];
                    s_lo = start[cur]; s_hi = start[cur + 1];
                    acc0=0.f; acc1=0.f; av0=0.f; av1=0.f; av2=0.f; bv0=0.f; bv1=0.f; bv2=0.f;
                }
                const float wa = blo(wv[j][0]), wb = bhi(wv[j][0]);
                const float wc = blo(wv[j][1]), wd = bhi(wv[j][1]);
                const float es  = blo(yd[j][0]), ev0 = bhi(yd[j][0]);
                const float ev1 = blo(yd[j][1]), ev2 = bhi(yd[j][1]);
                acc0 += wa * es * sh[j].x;
                acc1 += wd * (ev0*sh[j].y + ev1*sh[j].z + ev2*sh[j].w);  // 1/sqrt3 folded
                const float esb = wb * es;
                av0 += esb * sh[j].y; av1 += esb * sh[j].z; av2 += esb * sh[j].w;
                const float c0 = wc * sh[j].x;
                bv0 += c0 * ev0; bv1 += c0 * ev1; bv2 += c0 * ev2;
            }
        }
    }
    flushfn();
}

// ---------------- K3: node post-GEMM + RMS via MFMA (f32 ncat, bf16 sc) ----------------
__global__ __launch_bounds__(256) void k3_mfma(
    const float* __restrict__ ncat, const int* __restrict__ start,
    const short* __restrict__ wp2, const short* __restrict__ scpack,
    const float* __restrict__ gs, const float* __restrict__ gv,
    float* __restrict__ out)
{
    const int lane = threadIdx.x & 63;
    const int tile = blockIdx.x * 4 + (threadIdx.x >> 6);
    if (tile >= N_TILES) return;
    const int l15 = lane & 15, lhi = lane >> 4;
    const int n = tile*16 + l15;
    const f32x4 zz = {0.f, 0.f, 0.f, 0.f};
    f32x4 acc[4][4];
    #pragma unroll
    for (int c = 0; c < 4; ++c)
        #pragma unroll
        for (int vt = 0; vt < 4; ++vt) acc[c][vt] = zz;

    #pragma unroll
    for (int kk = 0; kk < 4; ++kk) {
        const int u0 = (kk & 1)*32 + lhi*8;
        const int c = (kk >> 1)*4;
        float4 ld[8];
        #pragma unroll
        for (int j = 0; j < 8; ++j)
            ld[j] = *(const float4*)(ncat + ((size_t)n*64 + u0 + j)*8 + c);
        union { u32x4 u; bf16x8 v; } bs, b0, b1, b2;
        #pragma unroll
        for (int q = 0; q < 4; ++q) {
            bs.u[q] = cvt_pk(ld[2*q].x, ld[2*q+1].x);
            b0.u[q] = cvt_pk(ld[2*q].y, ld[2*q+1].y);
            b1.u[q] = cvt_pk(ld[2*q].z, ld[2*q+1].z);
            b2.u[q] = cvt_pk(ld[2*q].w, ld[2*q+1].w);
        }
        #pragma unroll
        for (int vt = 0; vt < 4; ++vt) {
            const int fo = ((vt*4 + kk)*64 + lane)*8;
            const bf16x8 a_s = *(const bf16x8*)&wp2[fo];
            const bf16x8 a_v = *(const bf16x8*)&wp2[8192 + fo];
            acc[0][vt] = MFMA16(a_s, bs.v, acc[0][vt]);
            acc[1][vt] = MFMA16(a_v, b0.v, acc[1][vt]);
            acc[2][vt] = MFMA16(a_v, b1.v, acc[2][vt]);
            acc[3][vt] = MFMA16(a_v, b2.v, acc[3][vt]);
        }
    }
    const float degf = (float)(start[n+1] - start[n]);
    const float coef = rsqrtf(fmaxf(degf, 1.0f)) * 0.08838834764831845f;
    float os[4][4], o0[4][4], o1[4][4], o2[4][4];
    float ssq = 0.f, vsq = 0.f;
    #pragma unroll
    for (int vt = 0; vt < 4; ++vt)
        #pragma unroll
        for (int r = 0; r < 4; ++r) {
            const int v = vt*16 + lhi*4 + r;
            const u32x2 sc = *(const u32x2*)&scpack[((size_t)n*64 + v)*4];
            os[vt][r] = acc[0][vt][r]*coef + blo(sc[0]);
            o0[vt][r] = acc[1][vt][r]*coef + bhi(sc[0]);
            o1[vt][r] = acc[2][vt][r]*coef + blo(sc[1]);
            o2[vt][r] = acc[3][vt][r]*coef + bhi(sc[1]);
            ssq += os[vt][r]*os[vt][r];
            vsq += o0[vt][r]*o0[vt][r] + o1[vt][r]*o1[vt][r] + o2[vt][r]*o2[vt][r];
        }
    ssq += __shfl_xor(ssq, 16); ssq += __shfl_xor(ssq, 32);
    vsq += __shfl_xor(vsq, 16); vsq += __shfl_xor(vsq, 32);
    const float rs = rsqrtf(ssq * (1.0f/64.0f) + 1e-5f);
    const float rv = rsqrtf(vsq * (1.0f/192.0f) + 1e-5f);
    float* orow = out + (size_t)n * 256;
    #pragma unroll
    for (int vt = 0; vt < 4; ++vt) {
        const int vb = vt*16 + lhi*4;
        const float4 g4  = *(const float4*)(gs + vb);
        const float4 gv4 = *(const float4*)(gv + vb);
        const float4 so = { os[vt][0]*rs*g4.x, os[vt][1]*rs*g4.y,
                            os[vt][2]*rs*g4.z, os[vt][3]*rs*g4.w };
        *(float4*)(orow + vb) = so;
        const float m0 = rv*gv4.x, m1 = rv*gv4.y, m2 = rv*gv4.z, m3 = rv*gv4.w;
        const float4 w0 = { o0[vt][0]*m0, o1[vt][0]*m0, o2[vt][0]*m0, o0[vt][1]*m1 };
        const float4 w1 = { o1[vt][1]*m1, o2[vt][1]*m1, o0[vt][2]*m2, o1[vt][2]*m2 };
        const float4 w2 = { o2[vt][2]*m2, o0[vt][3]*m3, o1[vt][3]*m3, o2[vt][3]*m3 };
        float* vbase = orow + 64 + vb*3;
        *(float4*)(vbase)     = w0;
        *(float4*)(vbase + 4) = w1;
        *(float4*)(vbase + 8) = w2;
    }
}

extern "C" void kernel_launch(void* const* d_in, const int* in_sizes, int n_in,
                              void* d_out, int out_size, void* d_ws, size_t ws_size,
                              hipStream_t stream) {
    const float* nh   = (const float*)d_in[0];
    const float* ea   = (const float*)d_in[1];
    const float* esh  = (const float*)d_in[2];
    const float* w1s  = (const float*)d_in[3];
    const float* w1v  = (const float*)d_in[4];
    const float* wscs = (const float*)d_in[5];
    const float* wscv = (const float*)d_in[6];
    const float* w2s  = (const float*)d_in[7];
    const float* w2v  = (const float*)d_in[8];
    const float* fcw1 = (const float*)d_in[9];
    const float* fcw2 = (const float*)d_in[10];
    const float* fcw3 = (const float*)d_in[11];
    const float* gs   = (const float*)d_in[12];
    const float* gv   = (const float*)d_in[13];
    const int*   eidx = (const int*)d_in[14];
    float* out = (float*)d_out;

    char* wsb = (char*)d_ws;
    size_t off = 0;
    short* ydata  = (short*)(wsb + off); off += (size_t)N_NODES * 256 * 2;     // bf16 [n][64][4]
    short* scpack = (short*)(wsb + off); off += (size_t)N_NODES * 256 * 2;     // bf16 [n][64][4]
    float* ncat   = (float*)(wsb + off); off += (size_t)N_NODES * 512 * 4;     // f32  [n][64][8]
    float* esh_perm = (float*)(wsb + off); off += (size_t)N_EDGES * 4 * 4;
    int* cnt       = (int*)(wsb + off); off += (size_t)N_NODES * 4;
    int* start     = (int*)(wsb + off); off += ((size_t)N_NODES + 1) * 4;
    int* perm      = (int*)(wsb + off); off += (size_t)N_EDGES * 4;
    int* dst_perm  = (int*)(wsb + off); off += (size_t)N_EDGES * 4;
    int* node_perm = (int*)(wsb + off); off += (size_t)N_EDGES * 4;
    short* w1A = (short*)(wsb + off); off += 2048 * 2;
    short* w2A = (short*)(wsb + off); off += 4096 * 2;
    short* w3A = (short*)(wsb + off); off += 16384 * 2;
    short* wp1 = (short*)(wsb + off); off += 16384 * 2;
    short* wp2 = (short*)(wsb + off); off += 16384 * 2;

    hipMemsetAsync(cnt, 0, N_NODES * sizeof(int), stream);
    hipMemsetAsync(ncat, 0, (size_t)N_NODES * 512 * sizeof(float), stream);

    s_hist<<<(N_EDGES + 255)/256, 256, 0, stream>>>(eidx, cnt);
    s_scan<<<1, 1024, 0, stream>>>(cnt, start);
    s_scatter<<<(N_EDGES + 255)/256, 256, 0, stream>>>(
        eidx, esh, cnt, perm, dst_perm, node_perm, esh_perm);

    k_pack<<<32, 256, 0, stream>>>(fcw1, fcw2, fcw3, w1s, wscs, w1v, wscv,
                                   w2s, w2v, w1A, w2A, w3A, wp1, wp2);

    k1_mfma<<<(N_TILES + 3)/4, 256, 0, stream>>>(nh, wp1, ydata, scpack);

    k_msg<<<N_EDGES/256, 256, 0, stream>>>(
        ea, perm, dst_perm, node_perm, start, esh_perm,
        w1A, w2A, w3A, ydata, ncat);

    k3_mfma<<<(N_TILES + 3)/4, 256, 0, stream>>>(
        ncat, start, wp2, scpack, gs, gv, out);
}

// Round 12
// 222.664 us; speedup vs baseline: 1.4328x; 1.4328x over previous
//
#include <hip/hip_runtime.h>
#include <math.h>

#define N_NODES 20000
#define N_EDGES 320000
#define N_TILES 1250   // N_NODES / 16

typedef __attribute__((ext_vector_type(8))) short bf16x8;
typedef __attribute__((ext_vector_type(4))) float f32x4;
typedef __attribute__((ext_vector_type(2))) unsigned u32x2;
typedef __attribute__((ext_vector_type(4))) unsigned u32x4;

__device__ __forceinline__ float silu_f(float x) {
    return x / (1.0f + __expf(-x));
}
__device__ __forceinline__ short f2bf(float x) {
    union { float f; unsigned u; } v; v.f = x;
    unsigned r = (v.u + 0x7FFFu + ((v.u >> 16) & 1u)) >> 16;
    return (short)r;
}
__device__ __forceinline__ float blo(unsigned u) { return __uint_as_float(u << 16); }
__device__ __forceinline__ float bhi(unsigned u) { return __uint_as_float(u & 0xFFFF0000u); }
__device__ __forceinline__ unsigned cvt_pk(float lo, float hi) {
    unsigned r;
    asm("v_cvt_pk_bf16_f32 %0, %1, %2" : "=v"(r) : "v"(lo), "v"(hi));
    return r;
}
#define MFMA16(a, b, c) __builtin_amdgcn_mfma_f32_16x16x32_bf16((a), (b), (c), 0, 0, 0)

// ---------------- sort pass ----------------
__global__ __launch_bounds__(256) void s_hist(const int* __restrict__ eidx,
                                              int* __restrict__ cnt) {
    const int e = blockIdx.x * 256 + threadIdx.x;
    if (e < N_EDGES) atomicAdd(&cnt[eidx[e]], 1);
}

__global__ __launch_bounds__(1024) void s_scan(int* __restrict__ cnt,
                                               int* __restrict__ start) {
    const int tid = threadIdx.x;
    const int base = tid * 20;
    int vals[20];
    int sum = 0;
    #pragma unroll
    for (int j = 0; j < 20; ++j) {
        const int i = base + j;
        const int v = (i < N_NODES) ? cnt[i] : 0;
        vals[j] = sum;
        sum += v;
    }
    const int lane = tid & 63, wv = tid >> 6;
    int x = sum;
    #pragma unroll
    for (int off = 1; off < 64; off <<= 1) {
        const int t = __shfl_up(x, off);
        if (lane >= off) x += t;
    }
    __shared__ int wtot[16];
    if (lane == 63) wtot[wv] = x;
    __syncthreads();
    int wpref = 0;
    for (int k = 0; k < wv; ++k) wpref += wtot[k];
    const int excl = wpref + x - sum;
    #pragma unroll
    for (int j = 0; j < 20; ++j) {
        const int i = base + j;
        if (i < N_NODES) {
            const int s = excl + vals[j];
            start[i] = s;
            cnt[i] = s;   // cnt doubles as cursor
        }
    }
    if (tid == 1023) start[N_NODES] = wpref + x;
}

__global__ __launch_bounds__(256) void s_scatter(const int* __restrict__ eidx,
                                                 const float* __restrict__ esh,
                                                 int* __restrict__ cursor,
                                                 int* __restrict__ perm,
                                                 int* __restrict__ dst_perm,
                                                 float* __restrict__ esh_perm) {
    const int e = blockIdx.x * 256 + threadIdx.x;
    if (e >= N_EDGES) return;
    const int src = eidx[e];
    const int pos = atomicAdd(&cursor[src], 1);
    perm[pos] = e;
    dst_perm[pos] = eidx[N_EDGES + e];
    *(float4*)(esh_perm + (size_t)pos * 4) = *(const float4*)(esh + (size_t)e * 4);
}

// ---------------- weight prepack ----------------
__global__ __launch_bounds__(256) void k_pack(
    const float* __restrict__ fcw1, const float* __restrict__ fcw2,
    const float* __restrict__ fcw3,
    const float* __restrict__ w1s, const float* __restrict__ wscs,
    const float* __restrict__ w1v, const float* __restrict__ wscv,
    const float* __restrict__ w2s, const float* __restrict__ w2v,
    short* __restrict__ w1A, short* __restrict__ w2A, short* __restrict__ w3A,
    short* __restrict__ wp1, short* __restrict__ wp2)
{
    const int tid = blockIdx.x * 256 + threadIdx.x;
    const int nthr = gridDim.x * 256;
    for (int i = tid; i < 4*64*8; i += nthr) {           // fc_w1^T, K padded
        const int j = i & 7, lane = (i >> 3) & 63, t = i >> 9;
        const int k = (lane >> 4) * 8 + j, row = t*16 + (lane & 15);
        w1A[i] = (k < 8) ? f2bf(fcw1[k*64 + row]) : (short)0;
    }
    for (int i = tid; i < 8*64*8; i += nthr) {           // fc_w2^T
        const int j = i & 7, lane = (i >> 3) & 63, kk = (i >> 9) & 1, t = i >> 10;
        const int k = kk*32 + (lane >> 4)*8 + j, row = t*16 + (lane & 15);
        w2A[i] = f2bf(fcw2[k*64 + row]);
    }
    // fc_w3^T, stored in (c*4+q) band order so k_mlp's per-c loads are sequential.
    // band = q*4+c (ch = band*16 + l15); slot index Tp = c*4+q. wD (q==3) * 1/sqrt3 folded.
    for (int i = tid; i < 32*64*8; i += nthr) {
        const int j = i & 7, lane = (i >> 3) & 63, kk = (i >> 9) & 1, Tp = i >> 10;
        const int c = Tp >> 2, q = Tp & 3;
        const int k = kk*32 + (lane >> 4)*8 + j;
        const int ch = (q*4 + c)*16 + (lane & 15);
        const float s = (ch >= 192) ? 0.5773502691896258f : 1.0f;
        w3A[i] = f2bf(fcw3[(size_t)k*256 + ch] * s);
    }
    for (int i = tid; i < 4096; i += nthr) {             // k1 weights (64x64)
        const int j = i & 7, lane = (i >> 3) & 63, kk = (i >> 9) & 1, vt = i >> 10;
        const int row = vt*16 + (lane & 15), k = kk*32 + (lane >> 4)*8 + j;
        wp1[i]         = f2bf(w1s [k*64 + row]);
        wp1[4096 + i]  = f2bf(wscs[k*64 + row]);
        wp1[8192 + i]  = f2bf(w1v [k*64 + row]);
        wp1[12288 + i] = f2bf(wscv[k*64 + row]);
    }
    for (int i = tid; i < 8192; i += nthr) {             // k3 weights, k = u*2+bank remap
        const int j = i & 7, lane = (i >> 3) & 63, kk = (i >> 9) & 3, vt = i >> 11;
        const int row = vt*16 + (lane & 15), k = kk*32 + (lane >> 4)*8 + j;
        const int r = (k & 1)*64 + (k >> 1);
        wp2[i]        = f2bf(w2s[r*64 + row]);
        wp2[8192 + i] = f2bf(w2v[r*64 + row]);
    }
}

// ---------------- K1: node pre-GEMMs via MFMA, bf16-packed outputs ----------------
__global__ __launch_bounds__(256) void k1_mfma(
    const float* __restrict__ nh, const short* __restrict__ wp1,
    short* __restrict__ ydata, short* __restrict__ scpack)
{
    const int lane = threadIdx.x & 63;
    const int tile = blockIdx.x * 4 + (threadIdx.x >> 6);
    if (tile >= N_TILES) return;
    const int l15 = lane & 15, lhi = lane >> 4;
    const int n = tile*16 + l15;
    const float* row = nh + (size_t)n * 256;
    const f32x4 zz = {0.f, 0.f, 0.f, 0.f};
    f32x4 acc[8][4];
    #pragma unroll
    for (int c = 0; c < 8; ++c)
        #pragma unroll
        for (int vt = 0; vt < 4; ++vt) acc[c][vt] = zz;

    #pragma unroll
    for (int kk = 0; kk < 2; ++kk) {
        const int k0 = kk*32 + lhi*8;
        const float4 s0 = *(const float4*)(row + k0);
        const float4 s1 = *(const float4*)(row + k0 + 4);
        float4 vv[6];
        #pragma unroll
        for (int q = 0; q < 6; ++q) vv[q] = *(const float4*)(row + 64 + 3*k0 + q*4);
        const float* vf = (const float*)vv;
        union { u32x4 u; bf16x8 v; } bs, b0, b1, b2;
        bs.u[0] = cvt_pk(s0.x, s0.y); bs.u[1] = cvt_pk(s0.z, s0.w);
        bs.u[2] = cvt_pk(s1.x, s1.y); bs.u[3] = cvt_pk(s1.z, s1.w);
        #pragma unroll
        for (int q = 0; q < 4; ++q) {
            b0.u[q] = cvt_pk(vf[6*q + 0], vf[6*q + 3]);
            b1.u[q] = cvt_pk(vf[6*q + 1], vf[6*q + 4]);
            b2.u[q] = cvt_pk(vf[6*q + 2], vf[6*q + 5]);
        }
        #pragma unroll
        for (int vt = 0; vt < 4; ++vt) {
            const int fo = ((vt*2 + kk)*64 + lane)*8;
            const bf16x8 a_ys = *(const bf16x8*)&wp1[fo];
            const bf16x8 a_ss = *(const bf16x8*)&wp1[4096 + fo];
            const bf16x8 a_yv = *(const bf16x8*)&wp1[8192 + fo];
            const bf16x8 a_sv = *(const bf16x8*)&wp1[12288 + fo];
            acc[0][vt] = MFMA16(a_ys, bs.v, acc[0][vt]);
            acc[1][vt] = MFMA16(a_ss, bs.v, acc[1][vt]);
            acc[2][vt] = MFMA16(a_yv, b0.v, acc[2][vt]);
            acc[3][vt] = MFMA16(a_yv, b1.v, acc[3][vt]);
            acc[4][vt] = MFMA16(a_yv, b2.v, acc[4][vt]);
            acc[5][vt] = MFMA16(a_sv, b0.v, acc[5][vt]);
            acc[6][vt] = MFMA16(a_sv, b1.v, acc[6][vt]);
            acc[7][vt] = MFMA16(a_sv, b2.v, acc[7][vt]);
        }
    }
    #pragma unroll
    for (int vt = 0; vt < 4; ++vt)
        #pragma unroll
        for (int r = 0; r < 4; ++r) {
            const int v = vt*16 + lhi*4 + r;
            u32x2 yo, so;
            yo[0] = cvt_pk(acc[0][vt][r]*0.125f, acc[2][vt][r]*0.125f);
            yo[1] = cvt_pk(acc[3][vt][r]*0.125f, acc[4][vt][r]*0.125f);
            so[0] = cvt_pk(acc[1][vt][r]*0.125f, acc[5][vt][r]*0.125f);
            so[1] = cvt_pk(acc[6][vt][r]*0.125f, acc[7][vt][r]*0.125f);
            *(u32x2*)&ydata [((size_t)n*64 + v)*4] = yo;
            *(u32x2*)&scpack[((size_t)n*64 + v)*4] = so;
        }
}

// ---------------- K_mlp: MFMA edge MLP; 32 edges/wave, wq [slot][v][4ch] ----------------
__global__ __launch_bounds__(256) void k_mlp(
    const float* __restrict__ ea, const int* __restrict__ perm,
    const short* __restrict__ w1A, const short* __restrict__ w2A,
    const short* __restrict__ w3A, short* __restrict__ wq)
{
    __shared__ short hb1[4][1024];
    __shared__ short hb2[4][1024];
    const int lane = threadIdx.x & 63, w = threadIdx.x >> 6;
    const int l15 = lane & 15, lhi = lane >> 4;
    const int wbase = (blockIdx.x * 4 + w) * 32;
    short* h1b = hb1[w];
    short* h2b = hb2[w];
    const int swz = (l15 & 7) << 4;
    const f32x4 zz = {0.f, 0.f, 0.f, 0.f};

    bf16x8 a1[4], a2[4][2];
    #pragma unroll
    for (int t = 0; t < 4; ++t)
        a1[t] = *(const bf16x8*)&w1A[(t*64 + lane)*8];
    #pragma unroll
    for (int t = 0; t < 4; ++t)
        #pragma unroll
        for (int kk = 0; kk < 2; ++kk)
            a2[t][kk] = *(const bf16x8*)&w2A[((t*2 + kk)*64 + lane)*8];

    bf16x8 bh2[2][2];
    #pragma unroll
    for (int sb = 0; sb < 2; ++sb) {
        bf16x8 bea = {0,0,0,0,0,0,0,0};
        if (lhi == 0) {
            const int e = perm[wbase + sb*16 + l15];
            const float4 p0 = *(const float4*)(ea + (size_t)e*8);
            const float4 p1 = *(const float4*)(ea + (size_t)e*8 + 4);
            union { u32x4 u; bf16x8 v; } tu;
            tu.u[0] = cvt_pk(p0.x, p0.y);
            tu.u[1] = cvt_pk(p0.z, p0.w);
            tu.u[2] = cvt_pk(p1.x, p1.y);
            tu.u[3] = cvt_pk(p1.z, p1.w);
            bea = tu.v;
        }
        f32x4 d1[4];
        #pragma unroll
        for (int t = 0; t < 4; ++t)
            d1[t] = MFMA16(a1[t], bea, zz);
        #pragma unroll
        for (int t = 0; t < 4; ++t) {
            const float s0 = silu_f(d1[t][0] * 0.35355339059327373f);
            const float s1 = silu_f(d1[t][1] * 0.35355339059327373f);
            const float s2 = silu_f(d1[t][2] * 0.35355339059327373f);
            const float s3 = silu_f(d1[t][3] * 0.35355339059327373f);
            u32x2 pk; pk[0] = cvt_pk(s0, s1); pk[1] = cvt_pk(s2, s3);
            const int byt = (l15*128 + t*32 + lhi*8) ^ swz;
            *(u32x2*)((char*)h1b + byt) = pk;
        }
        bf16x8 bh1[2];
        #pragma unroll
        for (int kk = 0; kk < 2; ++kk)
            bh1[kk] = *(const bf16x8*)((const char*)h1b + ((l15*128 + kk*64 + lhi*16) ^ swz));
        f32x4 d2[4];
        #pragma unroll
        for (int t = 0; t < 4; ++t) {
            d2[t] = MFMA16(a2[t][0], bh1[0], zz);
            d2[t] = MFMA16(a2[t][1], bh1[1], d2[t]);
        }
        #pragma unroll
        for (int t = 0; t < 4; ++t) {
            const float s0 = silu_f(d2[t][0] * 0.125f) * 0.125f;
            const float s1 = silu_f(d2[t][1] * 0.125f) * 0.125f;
            const float s2 = silu_f(d2[t][2] * 0.125f) * 0.125f;
            const float s3 = silu_f(d2[t][3] * 0.125f) * 0.125f;
            u32x2 pk; pk[0] = cvt_pk(s0, s1); pk[1] = cvt_pk(s2, s3);
            const int byt = (l15*128 + t*32 + lhi*8) ^ swz;
            *(u32x2*)((char*)h2b + byt) = pk;
        }
        #pragma unroll
        for (int kk = 0; kk < 2; ++kk)
            bh2[sb][kk] = *(const bf16x8*)((const char*)h2b + ((l15*128 + kk*64 + lhi*16) ^ swz));
    }

    // L3 grouped by v-band c (w3A stored in (c*4+q) order -> sequential loads)
    #pragma unroll
    for (int c = 0; c < 4; ++c) {
        f32x4 dq[4][2];  // [q][sb]
        #pragma unroll
        for (int q = 0; q < 4; ++q) {
            const int Tp = c*4 + q;
            const bf16x8 a30 = *(const bf16x8*)&w3A[((Tp*2 + 0)*64 + lane)*8];
            const bf16x8 a31 = *(const bf16x8*)&w3A[((Tp*2 + 1)*64 + lane)*8];
            #pragma unroll
            for (int sb = 0; sb < 2; ++sb) {
                f32x4 d = MFMA16(a30, bh2[sb][0], zz);
                dq[q][sb] = MFMA16(a31, bh2[sb][1], d);
            }
        }
        // per lane: 4 consecutive v (r=0..3) x 8B = 32B contiguous -> two 16B stores
        #pragma unroll
        for (int sb = 0; sb < 2; ++sb) {
            const int slot = wbase + sb*16 + l15;
            const int vbase = c*16 + lhi*4;
            u32x4 lo, hi;
            lo[0] = cvt_pk(dq[0][sb][0], dq[1][sb][0]);
            lo[1] = cvt_pk(dq[2][sb][0], dq[3][sb][0]);
            lo[2] = cvt_pk(dq[0][sb][1], dq[1][sb][1]);
            lo[3] = cvt_pk(dq[2][sb][1], dq[3][sb][1]);
            hi[0] = cvt_pk(dq[0][sb][2], dq[1][sb][2]);
            hi[1] = cvt_pk(dq[2][sb][2], dq[3][sb][2]);
            hi[2] = cvt_pk(dq[0][sb][3], dq[1][sb][3]);
            hi[3] = cvt_pk(dq[2][sb][3], dq[3][sb][3]);
            short* base = &wq[((size_t)slot*64 + vbase)*4];
            *(u32x4*)(base)     = lo;
            *(u32x4*)(base + 8) = hi;
        }
    }
}

// ---------------- K2: per-node gather + register segment-sum ----------------
__global__ __launch_bounds__(256) void k2_gather(
    const int* __restrict__ start, const int* __restrict__ dst_perm,
    const float* __restrict__ esh_perm, const short* __restrict__ wq,
    const short* __restrict__ ydata, unsigned* __restrict__ ncat32)
{
    const int lane = threadIdx.x & 63;
    const int n = blockIdx.x * 4 + (threadIdx.x >> 6);
    if (n >= N_NODES) return;
    const int s0 = start[n], s1 = start[n + 1];
    float acc0=0.f, acc1=0.f, av0=0.f, av1=0.f, av2=0.f, bv0=0.f, bv1=0.f, bv2=0.f;
    for (int p = s0; p < s1; p += 8) {
        const int m = s1 - p;
        u32x2 wv[8], yd[8];
        float4 sh[8];
        #pragma unroll
        for (int j = 0; j < 8; ++j) {
            const int pp = (j < m) ? p + j : s0;
            wv[j] = *(const u32x2*)&wq[((size_t)pp*64 + lane)*4];
            sh[j] = *(const float4*)(esh_perm + (size_t)pp*4);
            const int dst = dst_perm[pp];
            yd[j] = *(const u32x2*)&ydata[((size_t)dst*64 + lane)*4];
        }
        #pragma unroll
        for (int j = 0; j < 8; ++j) {
            const float g = (j < m) ? 1.f : 0.f;
            const float wa = blo(wv[j][0])*g, wb = bhi(wv[j][0])*g;
            const float wc = blo(wv[j][1])*g, wd = bhi(wv[j][1])*g;
            const float es  = blo(yd[j][0]), ev0 = bhi(yd[j][0]);
            const float ev1 = blo(yd[j][1]), ev2 = bhi(yd[j][1]);
            acc0 += wa * es * sh[j].x;
            acc1 += wd * (ev0*sh[j].y + ev1*sh[j].z + ev2*sh[j].w);  // 1/sqrt3 folded
            const float esb = wb * es;
            av0 += esb * sh[j].y; av1 += esb * sh[j].z; av2 += esb * sh[j].w;
            const float c0 = wc * sh[j].x;
            bv0 += c0 * ev0; bv1 += c0 * ev1; bv2 += c0 * ev2;
        }
    }
    unsigned* nrow = ncat32 + (size_t)n * 256;
    nrow[lane]        = cvt_pk(acc0, acc1);
    nrow[64  + lane]  = cvt_pk(av0, bv0);
    nrow[128 + lane]  = cvt_pk(av1, bv1);
    nrow[192 + lane]  = cvt_pk(av2, bv2);
}

// ---------------- K3: node post-GEMM + RMS via MFMA, fragment-direct ncat ----------------
__global__ __launch_bounds__(256) void k3_mfma(
    const unsigned* __restrict__ ncat32, const int* __restrict__ start,
    const short* __restrict__ wp2, const short* __restrict__ scpack,
    const float* __restrict__ gs, const float* __restrict__ gv,
    float* __restrict__ out)
{
    const int lane = threadIdx.x & 63;
    const int tile = blockIdx.x * 4 + (threadIdx.x >> 6);
    if (tile >= N_TILES) return;
    const int l15 = lane & 15, lhi = lane >> 4;
    const int n = tile*16 + l15;
    const f32x4 zz = {0.f, 0.f, 0.f, 0.f};
    f32x4 acc[4][4];
    #pragma unroll
    for (int c = 0; c < 4; ++c)
        #pragma unroll
        for (int vt = 0; vt < 4; ++vt) acc[c][vt] = zz;

    const size_t nb = (size_t)n * 256;
    #pragma unroll
    for (int kk = 0; kk < 4; ++kk) {
        const int uo = kk*16 + lhi*4;
        union { u32x4 u; bf16x8 v; } bs, b0, b1, b2;
        bs.u = *(const u32x4*)&ncat32[nb +        uo];
        b0.u = *(const u32x4*)&ncat32[nb +  64 + uo];
        b1.u = *(const u32x4*)&ncat32[nb + 128 + uo];
        b2.u = *(const u32x4*)&ncat32[nb + 192 + uo];
        #pragma unroll
        for (int vt = 0; vt < 4; ++vt) {
            const int fo = ((vt*4 + kk)*64 + lane)*8;
            const bf16x8 a_s = *(const bf16x8*)&wp2[fo];
            const bf16x8 a_v = *(const bf16x8*)&wp2[8192 + fo];
            acc[0][vt] = MFMA16(a_s, bs.v, acc[0][vt]);
            acc[1][vt] = MFMA16(a_v, b0.v, acc[1][vt]);
            acc[2][vt] = MFMA16(a_v, b1.v, acc[2][vt]);
            acc[3][vt] = MFMA16(a_v, b2.v, acc[3][vt]);
        }
    }
    const float degf = (float)(start[n+1] - start[n]);
    const float coef = rsqrtf(fmaxf(degf, 1.0f)) * 0.08838834764831845f;
    float os[4][4], o0[4][4], o1[4][4], o2[4][4];
    float ssq = 0.f, vsq = 0.f;
    #pragma unroll
    for (int vt = 0; vt < 4; ++vt)
        #pragma unroll
        for (int r = 0; r < 4; ++r) {
            const int v = vt*16 + lhi*4 + r;
            const u32x2 sc = *(const u32x2*)&scpack[((size_t)n*64 + v)*4];
            os[vt][r] = acc[0][vt][r]*coef + blo(sc[0]);
            o0[vt][r] = acc[1][vt][r]*coef + bhi(sc[0]);
            o1[vt][r] = acc[2][vt][r]*coef + blo(sc[1]);
            o2[vt][r] = acc[3][vt][r]*coef + bhi(sc[1]);
            ssq += os[vt][r]*os[vt][r];
            vsq += o0[vt][r]*o0[vt][r] + o1[vt][r]*o1[vt][r] + o2[vt][r]*o2[vt][r];
        }
    ssq += __shfl_xor(ssq, 16); ssq += __shfl_xor(ssq, 32);
    vsq += __shfl_xor(vsq, 16); vsq += __shfl_xor(vsq, 32);
    const float rs = rsqrtf(ssq * (1.0f/64.0f) + 1e-5f);
    const float rv = rsqrtf(vsq * (1.0f/192.0f) + 1e-5f);
    float* orow = out + (size_t)n * 256;
    #pragma unroll
    for (int vt = 0; vt < 4; ++vt) {
        const int vb = vt*16 + lhi*4;
        const float4 g4  = *(const float4*)(gs + vb);
        const float4 gv4 = *(const float4*)(gv + vb);
        const float4 so = { os[vt][0]*rs*g4.x, os[vt][1]*rs*g4.y,
                            os[vt][2]*rs*g4.z, os[vt][3]*rs*g4.w };
        *(float4*)(orow + vb) = so;
        const float m0 = rv*gv4.x, m1 = rv*gv4.y, m2 = rv*gv4.z, m3 = rv*gv4.w;
        const float4 w0 = { o0[vt][0]*m0, o1[vt][0]*m0, o2[vt][0]*m0, o0[vt][1]*m1 };
        const float4 w1 = { o1[vt][1]*m1, o2[vt][1]*m1, o0[vt][2]*m2, o1[vt][2]*m2 };
        const float4 w2 = { o2[vt][2]*m2, o0[vt][3]*m3, o1[vt][3]*m3, o2[vt][3]*m3 };
        float* vbase = orow + 64 + vb*3;
        *(float4*)(vbase)     = w0;
        *(float4*)(vbase + 4) = w1;
        *(float4*)(vbase + 8) = w2;
    }
}

extern "C" void kernel_launch(void* const* d_in, const int* in_sizes, int n_in,
                              void* d_out, int out_size, void* d_ws, size_t ws_size,
                              hipStream_t stream) {
    const float* nh   = (const float*)d_in[0];
    const float* ea   = (const float*)d_in[1];
    const float* esh  = (const float*)d_in[2];
    const float* w1s  = (const float*)d_in[3];
    const float* w1v  = (const float*)d_in[4];
    const float* wscs = (const float*)d_in[5];
    const float* wscv = (const float*)d_in[6];
    const float* w2s  = (const float*)d_in[7];
    const float* w2v  = (const float*)d_in[8];
    const float* fcw1 = (const float*)d_in[9];
    const float* fcw2 = (const float*)d_in[10];
    const float* fcw3 = (const float*)d_in[11];
    const float* gs   = (const float*)d_in[12];
    const float* gv   = (const float*)d_in[13];
    const int*   eidx = (const int*)d_in[14];
    float* out = (float*)d_out;

    char* wsb = (char*)d_ws;
    size_t off = 0;
    short* ydata  = (short*)(wsb + off); off += (size_t)N_NODES * 256 * 2;     // bf16 [n][64][4]
    short* scpack = (short*)(wsb + off); off += (size_t)N_NODES * 256 * 2;     // bf16 [n][64][4]
    unsigned* ncat32 = (unsigned*)(wsb + off); off += (size_t)N_NODES * 256 * 4; // u32 [n][4][64]
    float* esh_perm  = (float*)(wsb + off); off += (size_t)N_EDGES * 4 * 4;
    int* cnt      = (int*)(wsb + off); off += (size_t)N_NODES * 4;
    int* start    = (int*)(wsb + off); off += ((size_t)N_NODES + 1) * 4;
    int* perm     = (int*)(wsb + off); off += (size_t)N_EDGES * 4;
    int* dst_perm = (int*)(wsb + off); off += (size_t)N_EDGES * 4;
    short* w1A = (short*)(wsb + off); off += 2048 * 2;
    short* w2A = (short*)(wsb + off); off += 4096 * 2;
    short* w3A = (short*)(wsb + off); off += 16384 * 2;
    short* wp1 = (short*)(wsb + off); off += 16384 * 2;
    short* wp2 = (short*)(wsb + off); off += 16384 * 2;
    off = (off + 15) & ~(size_t)15;
    short* wq = (short*)(wsb + off);

    hipMemsetAsync(cnt, 0, N_NODES * sizeof(int), stream);

    s_hist<<<(N_EDGES + 255)/256, 256, 0, stream>>>(eidx, cnt);
    s_scan<<<1, 1024, 0, stream>>>(cnt, start);
    s_scatter<<<(N_EDGES + 255)/256, 256, 0, stream>>>(
        eidx, esh, cnt, perm, dst_perm, esh_perm);

    k_pack<<<32, 256, 0, stream>>>(fcw1, fcw2, fcw3, w1s, wscs, w1v, wscv,
                                   w2s, w2v, w1A, w2A, w3A, wp1, wp2);

    k1_mfma<<<(N_TILES + 3)/4, 256, 0, stream>>>(nh, wp1, ydata, scpack);

    k_mlp<<<N_EDGES/128, 256, 0, stream>>>(ea, perm, w1A, w2A, w3A, wq);

    k2_gather<<<(N_NODES + 3)/4, 256, 0, stream>>>(
        start, dst_perm, esh_perm, wq, ydata, ncat32);

    k3_mfma<<<(N_TILES + 3)/4, 256, 0, stream>>>(
        ncat32, start, wp2, scpack, gs, gv, out);
}

// Round 13
// 218.304 us; speedup vs baseline: 1.4614x; 1.0200x over previous
//
#include <hip/hip_runtime.h>
#include <math.h>

#define N_NODES 20000
#define N_EDGES 320000
#define N_TILES 1250   // N_NODES / 16

typedef __attribute__((ext_vector_type(8))) short bf16x8;
typedef __attribute__((ext_vector_type(4))) float f32x4;
typedef __attribute__((ext_vector_type(2))) unsigned u32x2;
typedef __attribute__((ext_vector_type(4))) unsigned u32x4;

__device__ __forceinline__ float silu_f(float x) {
    return x / (1.0f + __expf(-x));
}
__device__ __forceinline__ short f2bf(float x) {
    union { float f; unsigned u; } v; v.f = x;
    unsigned r = (v.u + 0x7FFFu + ((v.u >> 16) & 1u)) >> 16;
    return (short)r;
}
__device__ __forceinline__ float blo(unsigned u) { return __uint_as_float(u << 16); }
__device__ __forceinline__ float bhi(unsigned u) { return __uint_as_float(u & 0xFFFF0000u); }
__device__ __forceinline__ unsigned cvt_pk(float lo, float hi) {
    unsigned r;
    asm("v_cvt_pk_bf16_f32 %0, %1, %2" : "=v"(r) : "v"(lo), "v"(hi));
    return r;
}
#define MFMA16(a, b, c) __builtin_amdgcn_mfma_f32_16x16x32_bf16((a), (b), (c), 0, 0, 0)

// ---------------- sort pass ----------------
__global__ __launch_bounds__(256) void s_hist(const int* __restrict__ eidx,
                                              int* __restrict__ cnt) {
    const int e = blockIdx.x * 256 + threadIdx.x;
    if (e < N_EDGES) atomicAdd(&cnt[eidx[e]], 1);
}

__global__ __launch_bounds__(1024) void s_scan(int* __restrict__ cnt,
                                               int* __restrict__ start) {
    const int tid = threadIdx.x;
    const int base = tid * 20;
    int vals[20];
    int sum = 0;
    #pragma unroll
    for (int j = 0; j < 20; ++j) {
        const int i = base + j;
        const int v = (i < N_NODES) ? cnt[i] : 0;
        vals[j] = sum;
        sum += v;
    }
    const int lane = tid & 63, wv = tid >> 6;
    int x = sum;
    #pragma unroll
    for (int off = 1; off < 64; off <<= 1) {
        const int t = __shfl_up(x, off);
        if (lane >= off) x += t;
    }
    __shared__ int wtot[16];
    if (lane == 63) wtot[wv] = x;
    __syncthreads();
    int wpref = 0;
    for (int k = 0; k < wv; ++k) wpref += wtot[k];
    const int excl = wpref + x - sum;
    #pragma unroll
    for (int j = 0; j < 20; ++j) {
        const int i = base + j;
        if (i < N_NODES) {
            const int s = excl + vals[j];
            start[i] = s;
            cnt[i] = s;   // cnt doubles as cursor
        }
    }
    if (tid == 1023) start[N_NODES] = wpref + x;
}

__global__ __launch_bounds__(256) void s_scatter(const int* __restrict__ eidx,
                                                 int* __restrict__ cursor,
                                                 int* __restrict__ perm) {
    const int e = blockIdx.x * 256 + threadIdx.x;
    if (e >= N_EDGES) return;
    const int src = eidx[e];
    const int pos = atomicAdd(&cursor[src], 1);
    perm[pos] = e;
}

// ---------------- weight prepack ----------------
__global__ __launch_bounds__(256) void k_pack(
    const float* __restrict__ fcw1, const float* __restrict__ fcw2,
    const float* __restrict__ fcw3,
    const float* __restrict__ w1s, const float* __restrict__ wscs,
    const float* __restrict__ w1v, const float* __restrict__ wscv,
    const float* __restrict__ w2s, const float* __restrict__ w2v,
    short* __restrict__ w1A, short* __restrict__ w2A, short* __restrict__ w3A,
    short* __restrict__ wp1, short* __restrict__ wp2)
{
    const int tid = blockIdx.x * 256 + threadIdx.x;
    const int nthr = gridDim.x * 256;
    for (int i = tid; i < 4*64*8; i += nthr) {           // fc_w1^T, K padded
        const int j = i & 7, lane = (i >> 3) & 63, t = i >> 9;
        const int k = (lane >> 4) * 8 + j, row = t*16 + (lane & 15);
        w1A[i] = (k < 8) ? f2bf(fcw1[k*64 + row]) : (short)0;
    }
    for (int i = tid; i < 8*64*8; i += nthr) {           // fc_w2^T
        const int j = i & 7, lane = (i >> 3) & 63, kk = (i >> 9) & 1, t = i >> 10;
        const int k = kk*32 + (lane >> 4)*8 + j, row = t*16 + (lane & 15);
        w2A[i] = f2bf(fcw2[k*64 + row]);
    }
    // fc_w3^T, stored in (c*4+q) band order so k_mlp's per-c loads are sequential.
    for (int i = tid; i < 32*64*8; i += nthr) {
        const int j = i & 7, lane = (i >> 3) & 63, kk = (i >> 9) & 1, Tp = i >> 10;
        const int c = Tp >> 2, q = Tp & 3;
        const int k = kk*32 + (lane >> 4)*8 + j;
        const int ch = (q*4 + c)*16 + (lane & 15);
        const float s = (ch >= 192) ? 0.5773502691896258f : 1.0f;
        w3A[i] = f2bf(fcw3[(size_t)k*256 + ch] * s);
    }
    for (int i = tid; i < 4096; i += nthr) {             // k1 weights (64x64)
        const int j = i & 7, lane = (i >> 3) & 63, kk = (i >> 9) & 1, vt = i >> 10;
        const int row = vt*16 + (lane & 15), k = kk*32 + (lane >> 4)*8 + j;
        wp1[i]         = f2bf(w1s [k*64 + row]);
        wp1[4096 + i]  = f2bf(wscs[k*64 + row]);
        wp1[8192 + i]  = f2bf(w1v [k*64 + row]);
        wp1[12288 + i] = f2bf(wscv[k*64 + row]);
    }
    for (int i = tid; i < 8192; i += nthr) {             // k3 weights, k = u*2+bank remap
        const int j = i & 7, lane = (i >> 3) & 63, kk = (i >> 9) & 3, vt = i >> 11;
        const int row = vt*16 + (lane & 15), k = kk*32 + (lane >> 4)*8 + j;
        const int r = (k & 1)*64 + (k >> 1);
        wp2[i]        = f2bf(w2s[r*64 + row]);
        wp2[8192 + i] = f2bf(w2v[r*64 + row]);
    }
}

// ---------------- K1: node pre-GEMMs via MFMA, bf16-packed outputs ----------------
__global__ __launch_bounds__(256) void k1_mfma(
    const float* __restrict__ nh, const short* __restrict__ wp1,
    short* __restrict__ ydata, short* __restrict__ scpack)
{
    const int lane = threadIdx.x & 63;
    const int tile = blockIdx.x * 4 + (threadIdx.x >> 6);
    if (tile >= N_TILES) return;
    const int l15 = lane & 15, lhi = lane >> 4;
    const int n = tile*16 + l15;
    const float* row = nh + (size_t)n * 256;
    const f32x4 zz = {0.f, 0.f, 0.f, 0.f};
    f32x4 acc[8][4];
    #pragma unroll
    for (int c = 0; c < 8; ++c)
        #pragma unroll
        for (int vt = 0; vt < 4; ++vt) acc[c][vt] = zz;

    #pragma unroll
    for (int kk = 0; kk < 2; ++kk) {
        const int k0 = kk*32 + lhi*8;
        const float4 s0 = *(const float4*)(row + k0);
        const float4 s1 = *(const float4*)(row + k0 + 4);
        float4 vv[6];
        #pragma unroll
        for (int q = 0; q < 6; ++q) vv[q] = *(const float4*)(row + 64 + 3*k0 + q*4);
        const float* vf = (const float*)vv;
        union { u32x4 u; bf16x8 v; } bs, b0, b1, b2;
        bs.u[0] = cvt_pk(s0.x, s0.y); bs.u[1] = cvt_pk(s0.z, s0.w);
        bs.u[2] = cvt_pk(s1.x, s1.y); bs.u[3] = cvt_pk(s1.z, s1.w);
        #pragma unroll
        for (int q = 0; q < 4; ++q) {
            b0.u[q] = cvt_pk(vf[6*q + 0], vf[6*q + 3]);
            b1.u[q] = cvt_pk(vf[6*q + 1], vf[6*q + 4]);
            b2.u[q] = cvt_pk(vf[6*q + 2], vf[6*q + 5]);
        }
        #pragma unroll
        for (int vt = 0; vt < 4; ++vt) {
            const int fo = ((vt*2 + kk)*64 + lane)*8;
            const bf16x8 a_ys = *(const bf16x8*)&wp1[fo];
            const bf16x8 a_ss = *(const bf16x8*)&wp1[4096 + fo];
            const bf16x8 a_yv = *(const bf16x8*)&wp1[8192 + fo];
            const bf16x8 a_sv = *(const bf16x8*)&wp1[12288 + fo];
            acc[0][vt] = MFMA16(a_ys, bs.v, acc[0][vt]);
            acc[1][vt] = MFMA16(a_ss, bs.v, acc[1][vt]);
            acc[2][vt] = MFMA16(a_yv, b0.v, acc[2][vt]);
            acc[3][vt] = MFMA16(a_yv, b1.v, acc[3][vt]);
            acc[4][vt] = MFMA16(a_yv, b2.v, acc[4][vt]);
            acc[5][vt] = MFMA16(a_sv, b0.v, acc[5][vt]);
            acc[6][vt] = MFMA16(a_sv, b1.v, acc[6][vt]);
            acc[7][vt] = MFMA16(a_sv, b2.v, acc[7][vt]);
        }
    }
    #pragma unroll
    for (int vt = 0; vt < 4; ++vt)
        #pragma unroll
        for (int r = 0; r < 4; ++r) {
            const int v = vt*16 + lhi*4 + r;
            u32x2 yo, so;
            yo[0] = cvt_pk(acc[0][vt][r]*0.125f, acc[2][vt][r]*0.125f);
            yo[1] = cvt_pk(acc[3][vt][r]*0.125f, acc[4][vt][r]*0.125f);
            so[0] = cvt_pk(acc[1][vt][r]*0.125f, acc[5][vt][r]*0.125f);
            so[1] = cvt_pk(acc[6][vt][r]*0.125f, acc[7][vt][r]*0.125f);
            *(u32x2*)&ydata [((size_t)n*64 + v)*4] = yo;
            *(u32x2*)&scpack[((size_t)n*64 + v)*4] = so;
        }
}

// ---------------- K_mlp: MFMA edge MLP; 32 edges/wave, wq [slot][v][4ch] ----------------
__global__ __launch_bounds__(256) void k_mlp(
    const float* __restrict__ ea, const int* __restrict__ perm,
    const short* __restrict__ w1A, const short* __restrict__ w2A,
    const short* __restrict__ w3A, short* __restrict__ wq)
{
    __shared__ short hb1[4][1024];
    __shared__ short hb2[4][1024];
    const int lane = threadIdx.x & 63, w = threadIdx.x >> 6;
    const int l15 = lane & 15, lhi = lane >> 4;
    const int wbase = (blockIdx.x * 4 + w) * 32;
    short* h1b = hb1[w];
    short* h2b = hb2[w];
    const int swz = (l15 & 7) << 4;
    const f32x4 zz = {0.f, 0.f, 0.f, 0.f};

    bf16x8 a1[4], a2[4][2];
    #pragma unroll
    for (int t = 0; t < 4; ++t)
        a1[t] = *(const bf16x8*)&w1A[(t*64 + lane)*8];
    #pragma unroll
    for (int t = 0; t < 4; ++t)
        #pragma unroll
        for (int kk = 0; kk < 2; ++kk)
            a2[t][kk] = *(const bf16x8*)&w2A[((t*2 + kk)*64 + lane)*8];

    bf16x8 bh2[2][2];
    #pragma unroll
    for (int sb = 0; sb < 2; ++sb) {
        bf16x8 bea = {0,0,0,0,0,0,0,0};
        if (lhi == 0) {
            const int e = perm[wbase + sb*16 + l15];
            const float4 p0 = *(const float4*)(ea + (size_t)e*8);
            const float4 p1 = *(const float4*)(ea + (size_t)e*8 + 4);
            union { u32x4 u; bf16x8 v; } tu;
            tu.u[0] = cvt_pk(p0.x, p0.y);
            tu.u[1] = cvt_pk(p0.z, p0.w);
            tu.u[2] = cvt_pk(p1.x, p1.y);
            tu.u[3] = cvt_pk(p1.z, p1.w);
            bea = tu.v;
        }
        f32x4 d1[4];
        #pragma unroll
        for (int t = 0; t < 4; ++t)
            d1[t] = MFMA16(a1[t], bea, zz);
        #pragma unroll
        for (int t = 0; t < 4; ++t) {
            const float s0 = silu_f(d1[t][0] * 0.35355339059327373f);
            const float s1 = silu_f(d1[t][1] * 0.35355339059327373f);
            const float s2 = silu_f(d1[t][2] * 0.35355339059327373f);
            const float s3 = silu_f(d1[t][3] * 0.35355339059327373f);
            u32x2 pk; pk[0] = cvt_pk(s0, s1); pk[1] = cvt_pk(s2, s3);
            const int byt = (l15*128 + t*32 + lhi*8) ^ swz;
            *(u32x2*)((char*)h1b + byt) = pk;
        }
        bf16x8 bh1[2];
        #pragma unroll
        for (int kk = 0; kk < 2; ++kk)
            bh1[kk] = *(const bf16x8*)((const char*)h1b + ((l15*128 + kk*64 + lhi*16) ^ swz));
        f32x4 d2[4];
        #pragma unroll
        for (int t = 0; t < 4; ++t) {
            d2[t] = MFMA16(a2[t][0], bh1[0], zz);
            d2[t] = MFMA16(a2[t][1], bh1[1], d2[t]);
        }
        #pragma unroll
        for (int t = 0; t < 4; ++t) {
            const float s0 = silu_f(d2[t][0] * 0.125f) * 0.125f;
            const float s1 = silu_f(d2[t][1] * 0.125f) * 0.125f;
            const float s2 = silu_f(d2[t][2] * 0.125f) * 0.125f;
            const float s3 = silu_f(d2[t][3] * 0.125f) * 0.125f;
            u32x2 pk; pk[0] = cvt_pk(s0, s1); pk[1] = cvt_pk(s2, s3);
            const int byt = (l15*128 + t*32 + lhi*8) ^ swz;
            *(u32x2*)((char*)h2b + byt) = pk;
        }
        #pragma unroll
        for (int kk = 0; kk < 2; ++kk)
            bh2[sb][kk] = *(const bf16x8*)((const char*)h2b + ((l15*128 + kk*64 + lhi*16) ^ swz));
    }

    // L3 grouped by v-band c (w3A stored in (c*4+q) order -> sequential loads)
    #pragma unroll
    for (int c = 0; c < 4; ++c) {
        f32x4 dq[4][2];  // [q][sb]
        #pragma unroll
        for (int q = 0; q < 4; ++q) {
            const int Tp = c*4 + q;
            const bf16x8 a30 = *(const bf16x8*)&w3A[((Tp*2 + 0)*64 + lane)*8];
            const bf16x8 a31 = *(const bf16x8*)&w3A[((Tp*2 + 1)*64 + lane)*8];
            #pragma unroll
            for (int sb = 0; sb < 2; ++sb) {
                f32x4 d = MFMA16(a30, bh2[sb][0], zz);
                dq[q][sb] = MFMA16(a31, bh2[sb][1], d);
            }
        }
        #pragma unroll
        for (int sb = 0; sb < 2; ++sb) {
            const int slot = wbase + sb*16 + l15;
            const int vbase = c*16 + lhi*4;
            u32x4 lo, hi;
            lo[0] = cvt_pk(dq[0][sb][0], dq[1][sb][0]);
            lo[1] = cvt_pk(dq[2][sb][0], dq[3][sb][0]);
            lo[2] = cvt_pk(dq[0][sb][1], dq[1][sb][1]);
            lo[3] = cvt_pk(dq[2][sb][1], dq[3][sb][1]);
            hi[0] = cvt_pk(dq[0][sb][2], dq[1][sb][2]);
            hi[1] = cvt_pk(dq[2][sb][2], dq[3][sb][2]);
            hi[2] = cvt_pk(dq[0][sb][3], dq[1][sb][3]);
            hi[3] = cvt_pk(dq[2][sb][3], dq[3][sb][3]);
            short* base = &wq[((size_t)slot*64 + vbase)*4];
            *(u32x4*)(base)     = lo;
            *(u32x4*)(base + 8) = hi;
        }
    }
}

// ---------------- K2: per-node gather + register segment-sum ----------------
// esh/eidx read through perm (random 4-16B loads, L2/L3-resident) instead of
// materialized permuted copies.
__global__ __launch_bounds__(256) void k2_gather(
    const int* __restrict__ start, const int* __restrict__ perm,
    const int* __restrict__ eidx, const float* __restrict__ esh,
    const short* __restrict__ wq, const short* __restrict__ ydata,
    unsigned* __restrict__ ncat32)
{
    const int lane = threadIdx.x & 63;
    const int n = blockIdx.x * 4 + (threadIdx.x >> 6);
    if (n >= N_NODES) return;
    const int s0 = start[n], s1 = start[n + 1];
    float acc0=0.f, acc1=0.f, av0=0.f, av1=0.f, av2=0.f, bv0=0.f, bv1=0.f, bv2=0.f;
    for (int p = s0; p < s1; p += 8) {
        const int m = s1 - p;
        u32x2 wv[8], yd[8];
        float4 sh[8];
        int e[8];
        #pragma unroll
        for (int j = 0; j < 8; ++j) {
            const int pp = (j < m) ? p + j : s0;
            e[j] = perm[pp];
            wv[j] = *(const u32x2*)&wq[((size_t)pp*64 + lane)*4];
        }
        #pragma unroll
        for (int j = 0; j < 8; ++j) {
            sh[j] = *(const float4*)(esh + (size_t)e[j]*4);
            const int dst = eidx[N_EDGES + e[j]];
            yd[j] = *(const u32x2*)&ydata[((size_t)dst*64 + lane)*4];
        }
        #pragma unroll
        for (int j = 0; j < 8; ++j) {
            const float g = (j < m) ? 1.f : 0.f;
            const float wa = blo(wv[j][0])*g, wb = bhi(wv[j][0])*g;
            const float wc = blo(wv[j][1])*g, wd = bhi(wv[j][1])*g;
            const float es  = blo(yd[j][0]), ev0 = bhi(yd[j][0]);
            const float ev1 = blo(yd[j][1]), ev2 = bhi(yd[j][1]);
            acc0 += wa * es * sh[j].x;
            acc1 += wd * (ev0*sh[j].y + ev1*sh[j].z + ev2*sh[j].w);  // 1/sqrt3 folded
            const float esb = wb * es;
            av0 += esb * sh[j].y; av1 += esb * sh[j].z; av2 += esb * sh[j].w;
            const float c0 = wc * sh[j].x;
            bv0 += c0 * ev0; bv1 += c0 * ev1; bv2 += c0 * ev2;
        }
    }
    unsigned* nrow = ncat32 + (size_t)n * 256;
    nrow[lane]        = cvt_pk(acc0, acc1);
    nrow[64  + lane]  = cvt_pk(av0, bv0);
    nrow[128 + lane]  = cvt_pk(av1, bv1);
    nrow[192 + lane]  = cvt_pk(av2, bv2);
}

// ---------------- K3: node post-GEMM + RMS via MFMA, fragment-direct ncat ----------------
__global__ __launch_bounds__(256) void k3_mfma(
    const unsigned* __restrict__ ncat32, const int* __restrict__ start,
    const short* __restrict__ wp2, const short* __restrict__ scpack,
    const float* __restrict__ gs, const float* __restrict__ gv,
    float* __restrict__ out)
{
    const int lane = threadIdx.x & 63;
    const int tile = blockIdx.x * 4 + (threadIdx.x >> 6);
    if (tile >= N_TILES) return;
    const int l15 = lane & 15, lhi = lane >> 4;
    const int n = tile*16 + l15;
    const f32x4 zz = {0.f, 0.f, 0.f, 0.f};
    f32x4 acc[4][4];
    #pragma unroll
    for (int c = 0; c < 4; ++c)
        #pragma unroll
        for (int vt = 0; vt < 4; ++vt) acc[c][vt] = zz;

    const size_t nb = (size_t)n * 256;
    #pragma unroll
    for (int kk = 0; kk < 4; ++kk) {
        const int uo = kk*16 + lhi*4;
        union { u32x4 u; bf16x8 v; } bs, b0, b1, b2;
        bs.u = *(const u32x4*)&ncat32[nb +        uo];
        b0.u = *(const u32x4*)&ncat32[nb +  64 + uo];
        b1.u = *(const u32x4*)&ncat32[nb + 128 + uo];
        b2.u = *(const u32x4*)&ncat32[nb + 192 + uo];
        #pragma unroll
        for (int vt = 0; vt < 4; ++vt) {
            const int fo = ((vt*4 + kk)*64 + lane)*8;
            const bf16x8 a_s = *(const bf16x8*)&wp2[fo];
            const bf16x8 a_v = *(const bf16x8*)&wp2[8192 + fo];
            acc[0][vt] = MFMA16(a_s, bs.v, acc[0][vt]);
            acc[1][vt] = MFMA16(a_v, b0.v, acc[1][vt]);
            acc[2][vt] = MFMA16(a_v, b1.v, acc[2][vt]);
            acc[3][vt] = MFMA16(a_v, b2.v, acc[3][vt]);
        }
    }
    const float degf = (float)(start[n+1] - start[n]);
    const float coef = rsqrtf(fmaxf(degf, 1.0f)) * 0.08838834764831845f;
    float os[4][4], o0[4][4], o1[4][4], o2[4][4];
    float ssq = 0.f, vsq = 0.f;
    #pragma unroll
    for (int vt = 0; vt < 4; ++vt)
        #pragma unroll
        for (int r = 0; r < 4; ++r) {
            const int v = vt*16 + lhi*4 + r;
            const u32x2 sc = *(const u32x2*)&scpack[((size_t)n*64 + v)*4];
            os[vt][r] = acc[0][vt][r]*coef + blo(sc[0]);
            o0[vt][r] = acc[1][vt][r]*coef + bhi(sc[0]);
            o1[vt][r] = acc[2][vt][r]*coef + blo(sc[1]);
            o2[vt][r] = acc[3][vt][r]*coef + bhi(sc[1]);
            ssq += os[vt][r]*os[vt][r];
            vsq += o0[vt][r]*o0[vt][r] + o1[vt][r]*o1[vt][r] + o2[vt][r]*o2[vt][r];
        }
    ssq += __shfl_xor(ssq, 16); ssq += __shfl_xor(ssq, 32);
    vsq += __shfl_xor(vsq, 16); vsq += __shfl_xor(vsq, 32);
    const float rs = rsqrtf(ssq * (1.0f/64.0f) + 1e-5f);
    const float rv = rsqrtf(vsq * (1.0f/192.0f) + 1e-5f);
    float* orow = out + (size_t)n * 256;
    #pragma unroll
    for (int vt = 0; vt < 4; ++vt) {
        const int vb = vt*16 + lhi*4;
        const float4 g4  = *(const float4*)(gs + vb);
        const float4 gv4 = *(const float4*)(gv + vb);
        const float4 so = { os[vt][0]*rs*g4.x, os[vt][1]*rs*g4.y,
                            os[vt][2]*rs*g4.z, os[vt][3]*rs*g4.w };
        *(float4*)(orow + vb) = so;
        const float m0 = rv*gv4.x, m1 = rv*gv4.y, m2 = rv*gv4.z, m3 = rv*gv4.w;
        const float4 w0 = { o0[vt][0]*m0, o1[vt][0]*m0, o2[vt][0]*m0, o0[vt][1]*m1 };
        const float4 w1 = { o1[vt][1]*m1, o2[vt][1]*m1, o0[vt][2]*m2, o1[vt][2]*m2 };
        const float4 w2 = { o2[vt][2]*m2, o0[vt][3]*m3, o1[vt][3]*m3, o2[vt][3]*m3 };
        float* vbase = orow + 64 + vb*3;
        *(float4*)(vbase)     = w0;
        *(float4*)(vbase + 4) = w1;
        *(float4*)(vbase + 8) = w2;
    }
}

extern "C" void kernel_launch(void* const* d_in, const int* in_sizes, int n_in,
                              void* d_out, int out_size, void* d_ws, size_t ws_size,
                              hipStream_t stream) {
    const float* nh   = (const float*)d_in[0];
    const float* ea   = (const float*)d_in[1];
    const float* esh  = (const float*)d_in[2];
    const float* w1s  = (const float*)d_in[3];
    const float* w1v  = (const float*)d_in[4];
    const float* wscs = (const float*)d_in[5];
    const float* wscv = (const float*)d_in[6];
    const float* w2s  = (const float*)d_in[7];
    const float* w2v  = (const float*)d_in[8];
    const float* fcw1 = (const float*)d_in[9];
    const float* fcw2 = (const float*)d_in[10];
    const float* fcw3 = (const float*)d_in[11];
    const float* gs   = (const float*)d_in[12];
    const float* gv   = (const float*)d_in[13];
    const int*   eidx = (const int*)d_in[14];
    float* out = (float*)d_out;

    char* wsb = (char*)d_ws;
    size_t off = 0;
    short* ydata  = (short*)(wsb + off); off += (size_t)N_NODES * 256 * 2;       // bf16 [n][64][4]
    short* scpack = (short*)(wsb + off); off += (size_t)N_NODES * 256 * 2;       // bf16 [n][64][4]
    unsigned* ncat32 = (unsigned*)(wsb + off); off += (size_t)N_NODES * 256 * 4; // u32 [n][4][64]
    int* cnt      = (int*)(wsb + off); off += (size_t)N_NODES * 4;
    int* start    = (int*)(wsb + off); off += ((size_t)N_NODES + 1) * 4;
    int* perm     = (int*)(wsb + off); off += (size_t)N_EDGES * 4;
    short* w1A = (short*)(wsb + off); off += 2048 * 2;
    short* w2A = (short*)(wsb + off); off += 4096 * 2;
    short* w3A = (short*)(wsb + off); off += 16384 * 2;
    short* wp1 = (short*)(wsb + off); off += 16384 * 2;
    short* wp2 = (short*)(wsb + off); off += 16384 * 2;
    off = (off + 15) & ~(size_t)15;
    short* wq = (short*)(wsb + off);

    hipMemsetAsync(cnt, 0, N_NODES * sizeof(int), stream);

    s_hist<<<(N_EDGES + 255)/256, 256, 0, stream>>>(eidx, cnt);
    s_scan<<<1, 1024, 0, stream>>>(cnt, start);
    s_scatter<<<(N_EDGES + 255)/256, 256, 0, stream>>>(eidx, cnt, perm);

    k_pack<<<32, 256, 0, stream>>>(fcw1, fcw2, fcw3, w1s, wscs, w1v, wscv,
                                   w2s, w2v, w1A, w2A, w3A, wp1, wp2);

    k1_mfma<<<(N_TILES + 3)/4, 256, 0, stream>>>(nh, wp1, ydata, scpack);

    k_mlp<<<N_EDGES/128, 256, 0, stream>>>(ea, perm, w1A, w2A, w3A, wq);

    k2_gather<<<(N_NODES + 3)/4, 256, 0, stream>>>(
        start, perm, eidx, esh, wq, ydata, ncat32);

    k3_mfma<<<(N_TILES + 3)/4, 256, 0, stream>>>(
        ncat32, start, wp2, scpack, gs, gv, out);
}

// Round 14
// 198.868 us; speedup vs baseline: 1.6042x; 1.0977x over previous
//
#include <hip/hip_runtime.h>
#include <math.h>

#define N_NODES 20000
#define N_EDGES 320000
#define N_TILES 1250   // N_NODES / 16
#define PACK_BLOCKS 32
#define HIST_BLOCKS ((N_EDGES + 255) / 256)
#define SCAT_BLOCKS ((N_EDGES + 255) / 256)
#define K1_BLOCKS ((N_TILES + 3) / 4)

typedef __attribute__((ext_vector_type(8))) short bf16x8;
typedef __attribute__((ext_vector_type(4))) float f32x4;
typedef __attribute__((ext_vector_type(2))) unsigned u32x2;
typedef __attribute__((ext_vector_type(4))) unsigned u32x4;

__device__ __forceinline__ float silu_f(float x) {
    return x / (1.0f + __expf(-x));
}
__device__ __forceinline__ short f2bf(float x) {
    union { float f; unsigned u; } v; v.f = x;
    unsigned r = (v.u + 0x7FFFu + ((v.u >> 16) & 1u)) >> 16;
    return (short)r;
}
__device__ __forceinline__ float blo(unsigned u) { return __uint_as_float(u << 16); }
__device__ __forceinline__ float bhi(unsigned u) { return __uint_as_float(u & 0xFFFF0000u); }
__device__ __forceinline__ unsigned cvt_pk(float lo, float hi) {
    unsigned r;
    asm("v_cvt_pk_bf16_f32 %0, %1, %2" : "=v"(r) : "v"(lo), "v"(hi));
    return r;
}
#define MFMA16(a, b, c) __builtin_amdgcn_mfma_f32_16x16x32_bf16((a), (b), (c), 0, 0, 0)

// ---------------- merged: weight prepack + src histogram ----------------
__global__ __launch_bounds__(256) void kp_hist(
    const int* __restrict__ eidx, int* __restrict__ cnt,
    const float* __restrict__ fcw1, const float* __restrict__ fcw2,
    const float* __restrict__ fcw3,
    const float* __restrict__ w1s, const float* __restrict__ wscs,
    const float* __restrict__ w1v, const float* __restrict__ wscv,
    const float* __restrict__ w2s, const float* __restrict__ w2v,
    short* __restrict__ w1A, short* __restrict__ w2A, short* __restrict__ w3A,
    short* __restrict__ wp1, short* __restrict__ wp2)
{
    if (blockIdx.x >= PACK_BLOCKS) {
        const int e = (blockIdx.x - PACK_BLOCKS) * 256 + threadIdx.x;
        if (e < N_EDGES) atomicAdd(&cnt[eidx[e]], 1);
        return;
    }
    const int tid = blockIdx.x * 256 + threadIdx.x;
    const int nthr = PACK_BLOCKS * 256;
    for (int i = tid; i < 4*64*8; i += nthr) {           // fc_w1^T, K padded
        const int j = i & 7, lane = (i >> 3) & 63, t = i >> 9;
        const int k = (lane >> 4) * 8 + j, row = t*16 + (lane & 15);
        w1A[i] = (k < 8) ? f2bf(fcw1[k*64 + row]) : (short)0;
    }
    for (int i = tid; i < 8*64*8; i += nthr) {           // fc_w2^T
        const int j = i & 7, lane = (i >> 3) & 63, kk = (i >> 9) & 1, t = i >> 10;
        const int k = kk*32 + (lane >> 4)*8 + j, row = t*16 + (lane & 15);
        w2A[i] = f2bf(fcw2[k*64 + row]);
    }
    // fc_w3^T in (c*4+q) band order; wD (ch>=192) * 1/sqrt3 folded
    for (int i = tid; i < 32*64*8; i += nthr) {
        const int j = i & 7, lane = (i >> 3) & 63, kk = (i >> 9) & 1, Tp = i >> 10;
        const int c = Tp >> 2, q = Tp & 3;
        const int k = kk*32 + (lane >> 4)*8 + j;
        const int ch = (q*4 + c)*16 + (lane & 15);
        const float s = (ch >= 192) ? 0.5773502691896258f : 1.0f;
        w3A[i] = f2bf(fcw3[(size_t)k*256 + ch] * s);
    }
    for (int i = tid; i < 4096; i += nthr) {             // k1 weights (64x64)
        const int j = i & 7, lane = (i >> 3) & 63, kk = (i >> 9) & 1, vt = i >> 10;
        const int row = vt*16 + (lane & 15), k = kk*32 + (lane >> 4)*8 + j;
        wp1[i]         = f2bf(w1s [k*64 + row]);
        wp1[4096 + i]  = f2bf(wscs[k*64 + row]);
        wp1[8192 + i]  = f2bf(w1v [k*64 + row]);
        wp1[12288 + i] = f2bf(wscv[k*64 + row]);
    }
    for (int i = tid; i < 8192; i += nthr) {             // k3 weights, k = u*2+bank remap
        const int j = i & 7, lane = (i >> 3) & 63, kk = (i >> 9) & 3, vt = i >> 11;
        const int row = vt*16 + (lane & 15), k = kk*32 + (lane >> 4)*8 + j;
        const int r = (k & 1)*64 + (k >> 1);
        wp2[i]        = f2bf(w2s[r*64 + row]);
        wp2[8192 + i] = f2bf(w2v[r*64 + row]);
    }
}

// ---------------- scan (single block) ----------------
__global__ __launch_bounds__(1024) void s_scan(int* __restrict__ cnt,
                                               int* __restrict__ start) {
    const int tid = threadIdx.x;
    const int base = tid * 20;
    int vals[20];
    int sum = 0;
    #pragma unroll
    for (int j = 0; j < 20; ++j) {
        const int i = base + j;
        const int v = (i < N_NODES) ? cnt[i] : 0;
        vals[j] = sum;
        sum += v;
    }
    const int lane = tid & 63, wv = tid >> 6;
    int x = sum;
    #pragma unroll
    for (int off = 1; off < 64; off <<= 1) {
        const int t = __shfl_up(x, off);
        if (lane >= off) x += t;
    }
    __shared__ int wtot[16];
    if (lane == 63) wtot[wv] = x;
    __syncthreads();
    int wpref = 0;
    for (int k = 0; k < wv; ++k) wpref += wtot[k];
    const int excl = wpref + x - sum;
    #pragma unroll
    for (int j = 0; j < 20; ++j) {
        const int i = base + j;
        if (i < N_NODES) {
            const int s = excl + vals[j];
            start[i] = s;
            cnt[i] = s;   // cnt doubles as cursor
        }
    }
    if (tid == 1023) start[N_NODES] = wpref + x;
}

// ---------------- merged: scatter + K1 node pre-GEMMs ----------------
__global__ __launch_bounds__(256) void scat_k1(
    const int* __restrict__ eidx, int* __restrict__ cursor,
    int* __restrict__ perm, int* __restrict__ dst_perm,
    const float* __restrict__ nh, const short* __restrict__ wp1,
    short* __restrict__ ydata, short* __restrict__ scpack)
{
    if (blockIdx.x < SCAT_BLOCKS) {
        const int e = blockIdx.x * 256 + threadIdx.x;
        if (e < N_EDGES) {
            const int src = eidx[e];
            const int pos = atomicAdd(&cursor[src], 1);
            perm[pos] = e;
            dst_perm[pos] = eidx[N_EDGES + e];
        }
        return;
    }
    const int lane = threadIdx.x & 63;
    const int tile = (blockIdx.x - SCAT_BLOCKS) * 4 + (threadIdx.x >> 6);
    if (tile >= N_TILES) return;
    const int l15 = lane & 15, lhi = lane >> 4;
    const int n = tile*16 + l15;
    const float* row = nh + (size_t)n * 256;
    const f32x4 zz = {0.f, 0.f, 0.f, 0.f};
    f32x4 acc[8][4];
    #pragma unroll
    for (int c = 0; c < 8; ++c)
        #pragma unroll
        for (int vt = 0; vt < 4; ++vt) acc[c][vt] = zz;

    #pragma unroll
    for (int kk = 0; kk < 2; ++kk) {
        const int k0 = kk*32 + lhi*8;
        const float4 s0 = *(const float4*)(row + k0);
        const float4 s1 = *(const float4*)(row + k0 + 4);
        float4 vv[6];
        #pragma unroll
        for (int q = 0; q < 6; ++q) vv[q] = *(const float4*)(row + 64 + 3*k0 + q*4);
        const float* vf = (const float*)vv;
        union { u32x4 u; bf16x8 v; } bs, b0, b1, b2;
        bs.u[0] = cvt_pk(s0.x, s0.y); bs.u[1] = cvt_pk(s0.z, s0.w);
        bs.u[2] = cvt_pk(s1.x, s1.y); bs.u[3] = cvt_pk(s1.z, s1.w);
        #pragma unroll
        for (int q = 0; q < 4; ++q) {
            b0.u[q] = cvt_pk(vf[6*q + 0], vf[6*q + 3]);
            b1.u[q] = cvt_pk(vf[6*q + 1], vf[6*q + 4]);
            b2.u[q] = cvt_pk(vf[6*q + 2], vf[6*q + 5]);
        }
        #pragma unroll
        for (int vt = 0; vt < 4; ++vt) {
            const int fo = ((vt*2 + kk)*64 + lane)*8;
            const bf16x8 a_ys = *(const bf16x8*)&wp1[fo];
            const bf16x8 a_ss = *(const bf16x8*)&wp1[4096 + fo];
            const bf16x8 a_yv = *(const bf16x8*)&wp1[8192 + fo];
            const bf16x8 a_sv = *(const bf16x8*)&wp1[12288 + fo];
            acc[0][vt] = MFMA16(a_ys, bs.v, acc[0][vt]);
            acc[1][vt] = MFMA16(a_ss, bs.v, acc[1][vt]);
            acc[2][vt] = MFMA16(a_yv, b0.v, acc[2][vt]);
            acc[3][vt] = MFMA16(a_yv, b1.v, acc[3][vt]);
            acc[4][vt] = MFMA16(a_yv, b2.v, acc[4][vt]);
            acc[5][vt] = MFMA16(a_sv, b0.v, acc[5][vt]);
            acc[6][vt] = MFMA16(a_sv, b1.v, acc[6][vt]);
            acc[7][vt] = MFMA16(a_sv, b2.v, acc[7][vt]);
        }
    }
    #pragma unroll
    for (int vt = 0; vt < 4; ++vt)
        #pragma unroll
        for (int r = 0; r < 4; ++r) {
            const int v = vt*16 + lhi*4 + r;
            u32x2 yo, so;
            yo[0] = cvt_pk(acc[0][vt][r]*0.125f, acc[2][vt][r]*0.125f);
            yo[1] = cvt_pk(acc[3][vt][r]*0.125f, acc[4][vt][r]*0.125f);
            so[0] = cvt_pk(acc[1][vt][r]*0.125f, acc[5][vt][r]*0.125f);
            so[1] = cvt_pk(acc[6][vt][r]*0.125f, acc[7][vt][r]*0.125f);
            *(u32x2*)&ydata [((size_t)n*64 + v)*4] = yo;
            *(u32x2*)&scpack[((size_t)n*64 + v)*4] = so;
        }
}

// ---------------- K_mlp: MFMA edge MLP; 32 edges/wave, wq [slot][v][4ch] ----------------
__global__ __launch_bounds__(256) void k_mlp(
    const float* __restrict__ ea, const int* __restrict__ perm,
    const short* __restrict__ w1A, const short* __restrict__ w2A,
    const short* __restrict__ w3A, short* __restrict__ wq)
{
    __shared__ short hb1[4][1024];
    __shared__ short hb2[4][1024];
    const int lane = threadIdx.x & 63, w = threadIdx.x >> 6;
    const int l15 = lane & 15, lhi = lane >> 4;
    const int wbase = (blockIdx.x * 4 + w) * 32;
    short* h1b = hb1[w];
    short* h2b = hb2[w];
    const int swz = (l15 & 7) << 4;
    const f32x4 zz = {0.f, 0.f, 0.f, 0.f};

    bf16x8 a1[4], a2[4][2];
    #pragma unroll
    for (int t = 0; t < 4; ++t)
        a1[t] = *(const bf16x8*)&w1A[(t*64 + lane)*8];
    #pragma unroll
    for (int t = 0; t < 4; ++t)
        #pragma unroll
        for (int kk = 0; kk < 2; ++kk)
            a2[t][kk] = *(const bf16x8*)&w2A[((t*2 + kk)*64 + lane)*8];

    bf16x8 bh2[2][2];
    #pragma unroll
    for (int sb = 0; sb < 2; ++sb) {
        bf16x8 bea = {0,0,0,0,0,0,0,0};
        if (lhi == 0) {
            const int e = perm[wbase + sb*16 + l15];
            const float4 p0 = *(const float4*)(ea + (size_t)e*8);
            const float4 p1 = *(const float4*)(ea + (size_t)e*8 + 4);
            union { u32x4 u; bf16x8 v; } tu;
            tu.u[0] = cvt_pk(p0.x, p0.y);
            tu.u[1] = cvt_pk(p0.z, p0.w);
            tu.u[2] = cvt_pk(p1.x, p1.y);
            tu.u[3] = cvt_pk(p1.z, p1.w);
            bea = tu.v;
        }
        f32x4 d1[4];
        #pragma unroll
        for (int t = 0; t < 4; ++t)
            d1[t] = MFMA16(a1[t], bea, zz);
        #pragma unroll
        for (int t = 0; t < 4; ++t) {
            const float s0 = silu_f(d1[t][0] * 0.35355339059327373f);
            const float s1 = silu_f(d1[t][1] * 0.35355339059327373f);
            const float s2 = silu_f(d1[t][2] * 0.35355339059327373f);
            const float s3 = silu_f(d1[t][3] * 0.35355339059327373f);
            u32x2 pk; pk[0] = cvt_pk(s0, s1); pk[1] = cvt_pk(s2, s3);
            const int byt = (l15*128 + t*32 + lhi*8) ^ swz;
            *(u32x2*)((char*)h1b + byt) = pk;
        }
        bf16x8 bh1[2];
        #pragma unroll
        for (int kk = 0; kk < 2; ++kk)
            bh1[kk] = *(const bf16x8*)((const char*)h1b + ((l15*128 + kk*64 + lhi*16) ^ swz));
        f32x4 d2[4];
        #pragma unroll
        for (int t = 0; t < 4; ++t) {
            d2[t] = MFMA16(a2[t][0], bh1[0], zz);
            d2[t] = MFMA16(a2[t][1], bh1[1], d2[t]);
        }
        #pragma unroll
        for (int t = 0; t < 4; ++t) {
            const float s0 = silu_f(d2[t][0] * 0.125f) * 0.125f;
            const float s1 = silu_f(d2[t][1] * 0.125f) * 0.125f;
            const float s2 = silu_f(d2[t][2] * 0.125f) * 0.125f;
            const float s3 = silu_f(d2[t][3] * 0.125f) * 0.125f;
            u32x2 pk; pk[0] = cvt_pk(s0, s1); pk[1] = cvt_pk(s2, s3);
            const int byt = (l15*128 + t*32 + lhi*8) ^ swz;
            *(u32x2*)((char*)h2b + byt) = pk;
        }
        #pragma unroll
        for (int kk = 0; kk < 2; ++kk)
            bh2[sb][kk] = *(const bf16x8*)((const char*)h2b + ((l15*128 + kk*64 + lhi*16) ^ swz));
    }

    // L3 grouped by v-band c (w3A stored in (c*4+q) order -> sequential loads)
    #pragma unroll
    for (int c = 0; c < 4; ++c) {
        f32x4 dq[4][2];  // [q][sb]
        #pragma unroll
        for (int q = 0; q < 4; ++q) {
            const int Tp = c*4 + q;
            const bf16x8 a30 = *(const bf16x8*)&w3A[((Tp*2 + 0)*64 + lane)*8];
            const bf16x8 a31 = *(const bf16x8*)&w3A[((Tp*2 + 1)*64 + lane)*8];
            #pragma unroll
            for (int sb = 0; sb < 2; ++sb) {
                f32x4 d = MFMA16(a30, bh2[sb][0], zz);
                dq[q][sb] = MFMA16(a31, bh2[sb][1], d);
            }
        }
        #pragma unroll
        for (int sb = 0; sb < 2; ++sb) {
            const int slot = wbase + sb*16 + l15;
            const int vbase = c*16 + lhi*4;
            u32x4 lo, hi;
            lo[0] = cvt_pk(dq[0][sb][0], dq[1][sb][0]);
            lo[1] = cvt_pk(dq[2][sb][0], dq[3][sb][0]);
            lo[2] = cvt_pk(dq[0][sb][1], dq[1][sb][1]);
            lo[3] = cvt_pk(dq[2][sb][1], dq[3][sb][1]);
            hi[0] = cvt_pk(dq[0][sb][2], dq[1][sb][2]);
            hi[1] = cvt_pk(dq[2][sb][2], dq[3][sb][2]);
            hi[2] = cvt_pk(dq[0][sb][3], dq[1][sb][3]);
            hi[3] = cvt_pk(dq[2][sb][3], dq[3][sb][3]);
            short* base = &wq[((size_t)slot*64 + vbase)*4];
            *(u32x4*)(base)     = lo;
            *(u32x4*)(base + 8) = hi;
        }
    }
}

// ---------------- K2: per-node gather + register segment-sum ----------------
// perm/dst_perm/wq sequential; esh + ydata gathers 1-level deep, 8-batched.
__global__ __launch_bounds__(256) void k2_gather(
    const int* __restrict__ start, const int* __restrict__ perm,
    const int* __restrict__ dst_perm, const float* __restrict__ esh,
    const short* __restrict__ wq, const short* __restrict__ ydata,
    unsigned* __restrict__ ncat32)
{
    const int lane = threadIdx.x & 63;
    const int n = blockIdx.x * 4 + (threadIdx.x >> 6);
    if (n >= N_NODES) return;
    const int s0 = start[n], s1 = start[n + 1];
    float acc0=0.f, acc1=0.f, av0=0.f, av1=0.f, av2=0.f, bv0=0.f, bv1=0.f, bv2=0.f;
    for (int p = s0; p < s1; p += 8) {
        const int m = s1 - p;
        u32x2 wv[8], yd[8];
        float4 sh[8];
        int e[8], d[8];
        #pragma unroll
        for (int j = 0; j < 8; ++j) {
            const int pp = (j < m) ? p + j : s0;
            e[j] = perm[pp];
            d[j] = dst_perm[pp];
            wv[j] = *(const u32x2*)&wq[((size_t)pp*64 + lane)*4];
        }
        #pragma unroll
        for (int j = 0; j < 8; ++j) {
            sh[j] = *(const float4*)(esh + (size_t)e[j]*4);
            yd[j] = *(const u32x2*)&ydata[((size_t)d[j]*64 + lane)*4];
        }
        #pragma unroll
        for (int j = 0; j < 8; ++j) {
            const float g = (j < m) ? 1.f : 0.f;
            const float wa = blo(wv[j][0])*g, wb = bhi(wv[j][0])*g;
            const float wc = blo(wv[j][1])*g, wd = bhi(wv[j][1])*g;
            const float es  = blo(yd[j][0]), ev0 = bhi(yd[j][0]);
            const float ev1 = blo(yd[j][1]), ev2 = bhi(yd[j][1]);
            acc0 += wa * es * sh[j].x;
            acc1 += wd * (ev0*sh[j].y + ev1*sh[j].z + ev2*sh[j].w);  // 1/sqrt3 folded
            const float esb = wb * es;
            av0 += esb * sh[j].y; av1 += esb * sh[j].z; av2 += esb * sh[j].w;
            const float c0 = wc * sh[j].x;
            bv0 += c0 * ev0; bv1 += c0 * ev1; bv2 += c0 * ev2;
        }
    }
    unsigned* nrow = ncat32 + (size_t)n * 256;
    nrow[lane]        = cvt_pk(acc0, acc1);
    nrow[64  + lane]  = cvt_pk(av0, bv0);
    nrow[128 + lane]  = cvt_pk(av1, bv1);
    nrow[192 + lane]  = cvt_pk(av2, bv2);
}

// ---------------- K3: node post-GEMM + RMS via MFMA, fragment-direct ncat ----------------
__global__ __launch_bounds__(256) void k3_mfma(
    const unsigned* __restrict__ ncat32, const int* __restrict__ start,
    const short* __restrict__ wp2, const short* __restrict__ scpack,
    const float* __restrict__ gs, const float* __restrict__ gv,
    float* __restrict__ out)
{
    const int lane = threadIdx.x & 63;
    const int tile = blockIdx.x * 4 + (threadIdx.x >> 6);
    if (tile >= N_TILES) return;
    const int l15 = lane & 15, lhi = lane >> 4;
    const int n = tile*16 + l15;
    const f32x4 zz = {0.f, 0.f, 0.f, 0.f};
    f32x4 acc[4][4];
    #pragma unroll
    for (int c = 0; c < 4; ++c)
        #pragma unroll
        for (int vt = 0; vt < 4; ++vt) acc[c][vt] = zz;

    const size_t nb = (size_t)n * 256;
    #pragma unroll
    for (int kk = 0; kk < 4; ++kk) {
        const int uo = kk*16 + lhi*4;
        union { u32x4 u; bf16x8 v; } bs, b0, b1, b2;
        bs.u = *(const u32x4*)&ncat32[nb +        uo];
        b0.u = *(const u32x4*)&ncat32[nb +  64 + uo];
        b1.u = *(const u32x4*)&ncat32[nb + 128 + uo];
        b2.u = *(const u32x4*)&ncat32[nb + 192 + uo];
        #pragma unroll
        for (int vt = 0; vt < 4; ++vt) {
            const int fo = ((vt*4 + kk)*64 + lane)*8;
            const bf16x8 a_s = *(const bf16x8*)&wp2[fo];
            const bf16x8 a_v = *(const bf16x8*)&wp2[8192 + fo];
            acc[0][vt] = MFMA16(a_s, bs.v, acc[0][vt]);
            acc[1][vt] = MFMA16(a_v, b0.v, acc[1][vt]);
            acc[2][vt] = MFMA16(a_v, b1.v, acc[2][vt]);
            acc[3][vt] = MFMA16(a_v, b2.v, acc[3][vt]);
        }
    }
    const float degf = (float)(start[n+1] - start[n]);
    const float coef = rsqrtf(fmaxf(degf, 1.0f)) * 0.08838834764831845f;
    float os[4][4], o0[4][4], o1[4][4], o2[4][4];
    float ssq = 0.f, vsq = 0.f;
    #pragma unroll
    for (int vt = 0; vt < 4; ++vt)
        #pragma unroll
        for (int r = 0; r < 4; ++r) {
            const int v = vt*16 + lhi*4 + r;
            const u32x2 sc = *(const u32x2*)&scpack[((size_t)n*64 + v)*4];
            os[vt][r] = acc[0][vt][r]*coef + blo(sc[0]);
            o0[vt][r] = acc[1][vt][r]*coef + bhi(sc[0]);
            o1[vt][r] = acc[2][vt][r]*coef + blo(sc[1]);
            o2[vt][r] = acc[3][vt][r]*coef + bhi(sc[1]);
            ssq += os[vt][r]*os[vt][r];
            vsq += o0[vt][r]*o0[vt][r] + o1[vt][r]*o1[vt][r] + o2[vt][r]*o2[vt][r];
        }
    ssq += __shfl_xor(ssq, 16); ssq += __shfl_xor(ssq, 32);
    vsq += __shfl_xor(vsq, 16); vsq += __shfl_xor(vsq, 32);
    const float rs = rsqrtf(ssq * (1.0f/64.0f) + 1e-5f);
    const float rv = rsqrtf(vsq * (1.0f/192.0f) + 1e-5f);
    float* orow = out + (size_t)n * 256;
    #pragma unroll
    for (int vt = 0; vt < 4; ++vt) {
        const int vb = vt*16 + lhi*4;
        const float4 g4  = *(const float4*)(gs + vb);
        const float4 gv4 = *(const float4*)(gv + vb);
        const float4 so = { os[vt][0]*rs*g4.x, os[vt][1]*rs*g4.y,
                            os[vt][2]*rs*g4.z, os[vt][3]*rs*g4.w };
        *(float4*)(orow + vb) = so;
        const float m0 = rv*gv4.x, m1 = rv*gv4.y, m2 = rv*gv4.z, m3 = rv*gv4.w;
        const float4 w0 = { o0[vt][0]*m0, o1[vt][0]*m0, o2[vt][0]*m0, o0[vt][1]*m1 };
        const float4 w1 = { o1[vt][1]*m1, o2[vt][1]*m1, o0[vt][2]*m2, o1[vt][2]*m2 };
        const float4 w2 = { o2[vt][2]*m2, o0[vt][3]*m3, o1[vt][3]*m3, o2[vt][3]*m3 };
        float* vbase = orow + 64 + vb*3;
        *(float4*)(vbase)     = w0;
        *(float4*)(vbase + 4) = w1;
        *(float4*)(vbase + 8) = w2;
    }
}

extern "C" void kernel_launch(void* const* d_in, const int* in_sizes, int n_in,
                              void* d_out, int out_size, void* d_ws, size_t ws_size,
                              hipStream_t stream) {
    const float* nh   = (const float*)d_in[0];
    const float* ea   = (const float*)d_in[1];
    const float* esh  = (const float*)d_in[2];
    const float* w1s  = (const float*)d_in[3];
    const float* w1v  = (const float*)d_in[4];
    const float* wscs = (const float*)d_in[5];
    const float* wscv = (const float*)d_in[6];
    const float* w2s  = (const float*)d_in[7];
    const float* w2v  = (const float*)d_in[8];
    const float* fcw1 = (const float*)d_in[9];
    const float* fcw2 = (const float*)d_in[10];
    const float* fcw3 = (const float*)d_in[11];
    const float* gs   = (const float*)d_in[12];
    const float* gv   = (const float*)d_in[13];
    const int*   eidx = (const int*)d_in[14];
    float* out = (float*)d_out;

    char* wsb = (char*)d_ws;
    size_t off = 0;
    short* ydata  = (short*)(wsb + off); off += (size_t)N_NODES * 256 * 2;       // bf16 [n][64][4]
    short* scpack = (short*)(wsb + off); off += (size_t)N_NODES * 256 * 2;       // bf16 [n][64][4]
    unsigned* ncat32 = (unsigned*)(wsb + off); off += (size_t)N_NODES * 256 * 4; // u32 [n][4][64]
    int* cnt      = (int*)(wsb + off); off += (size_t)N_NODES * 4;
    int* start    = (int*)(wsb + off); off += ((size_t)N_NODES + 1) * 4;
    int* perm     = (int*)(wsb + off); off += (size_t)N_EDGES * 4;
    int* dst_perm = (int*)(wsb + off); off += (size_t)N_EDGES * 4;
    short* w1A = (short*)(wsb + off); off += 2048 * 2;
    short* w2A = (short*)(wsb + off); off += 4096 * 2;
    short* w3A = (short*)(wsb + off); off += 16384 * 2;
    short* wp1 = (short*)(wsb + off); off += 16384 * 2;
    short* wp2 = (short*)(wsb + off); off += 16384 * 2;
    off = (off + 15) & ~(size_t)15;
    short* wq = (short*)(wsb + off);

    hipMemsetAsync(cnt, 0, N_NODES * sizeof(int), stream);

    kp_hist<<<PACK_BLOCKS + HIST_BLOCKS, 256, 0, stream>>>(
        eidx, cnt, fcw1, fcw2, fcw3, w1s, wscs, w1v, wscv, w2s, w2v,
        w1A, w2A, w3A, wp1, wp2);

    s_scan<<<1, 1024, 0, stream>>>(cnt, start);

    scat_k1<<<SCAT_BLOCKS + K1_BLOCKS, 256, 0, stream>>>(
        eidx, cnt, perm, dst_perm, nh, wp1, ydata, scpack);

    k_mlp<<<N_EDGES/128, 256, 0, stream>>>(ea, perm, w1A, w2A, w3A, wq);

    k2_gather<<<(N_NODES + 3)/4, 256, 0, stream>>>(
        start, perm, dst_perm, esh, wq, ydata, ncat32);

    k3_mfma<<<(N_TILES + 3)/4, 256, 0, stream>>>(
        ncat32, start, wp2, scpack, gs, gv, out);
}